// Round 7
// baseline (672.616 us; speedup 1.0000x reference)
//
#include <hip/hip_runtime.h>
#include <hip/hip_bf16.h>
#include <stdint.h>

#define DEV static __device__ __forceinline__

typedef __attribute__((ext_vector_type(8))) short short8;   // 8 bf16 (4 VGPRs)
typedef __attribute__((ext_vector_type(4))) float f32x4;    // MFMA accumulator

DEV float bf2f(unsigned short u) { return __uint_as_float(((unsigned)u) << 16); }
DEV float bflo(unsigned u) { return __uint_as_float(u << 16); }
DEV float bfhi(unsigned u) { return __uint_as_float(u & 0xffff0000u); }
DEV unsigned short f2bf(float f) {
    unsigned u = __float_as_uint(f);
    u += 0x7fff + ((u >> 16) & 1);   // RNE
    return (unsigned short)(u >> 16);
}

// ---------------- edge_index width detection (int64 vs int32) ----------------
__global__ void k_detect(const int* __restrict__ ei, int* __restrict__ flags) {
    if (threadIdx.x == 0 && blockIdx.x == 0) {
        int zeros = 0;
        for (int i = 0; i < 128; ++i) if (ei[2 * i + 1] == 0) ++zeros;
        flags[1] = (zeros >= 64) ? 1 : 0;
    }
}

// fused: index narrow + degree count (saves a separate 800k-element pass)
__global__ void k_cvt_idx(const int* __restrict__ ei, int* __restrict__ src32,
                          int* __restrict__ dst32, int* __restrict__ deg,
                          int E, const int* __restrict__ flags) {
    int i = blockIdx.x * 256 + threadIdx.x;
    if (i >= E) return;
    int s, d;
    if (flags[1]) { s = ei[2 * i]; d = ei[2 * E + 2 * i]; }
    else          { s = ei[i];     d = ei[E + i]; }
    src32[i] = s; dst32[i] = d;
    atomicAdd(&deg[d], 1);
}

// ---------------- fused transpose+narrow: fp32 in[r][c] -> bf16 out[c][r] ----------------
__global__ void k_transpose_nb(const float* __restrict__ in, unsigned short* __restrict__ out,
                               int R, int C) {
    __shared__ unsigned short tile[32][33];
    int tx = threadIdx.x & 31, ty = threadIdx.x >> 5;   // 256 threads = 32x8
    size_t mat = (size_t)blockIdx.z * R * C;
    int r0 = blockIdx.y * 32, c0 = blockIdx.x * 32;
#pragma unroll
    for (int j = 0; j < 32; j += 8)
        tile[ty + j][tx] = f2bf(in[mat + (size_t)(r0 + ty + j) * C + c0 + tx]);
    __syncthreads();
#pragma unroll
    for (int j = 0; j < 32; j += 8)
        out[mat + (size_t)(c0 + ty + j) * R + r0 + tx] = tile[tx][ty + j];
}

// bias for the fused layer-3 GEMM: cols 0..127 (P half) get 0, cols 128..255 get bl3
__global__ void k_bias3(const float* __restrict__ bl3, float* __restrict__ bias3) {
    int t = threadIdx.x;
    bias3[t] = (t < 128) ? 0.f : bl3[t - 128];
}

// ---------------- CSR build: degree (fused above) -> 3-phase shfl scan -> fill ----------------
__global__ void k_scan1(const int* __restrict__ deg, int* __restrict__ row_ptr,
                        int* __restrict__ part, int n) {
    __shared__ int wsum[4];
    int t = threadIdx.x, lane = t & 63, wv = t >> 6;
    int i = blockIdx.x * 256 + t;
    int v0 = (i < n) ? deg[i] : 0;
    int v = v0;
#pragma unroll
    for (int d = 1; d < 64; d <<= 1) { int u = __shfl_up(v, d); if (lane >= d) v += u; }
    if (lane == 63) wsum[wv] = v;
    __syncthreads();
    int add = 0;
    for (int w2 = 0; w2 < wv; ++w2) add += wsum[w2];
    v += add;
    if (i < n) row_ptr[i] = v - v0;            // block-local exclusive
    if (t == 255) part[blockIdx.x] = v;        // block total
}

__global__ void k_scan2(int* __restrict__ part, int P) {
    __shared__ int wsum[4];
    int t = threadIdx.x, lane = t & 63, wv = t >> 6;
    int v0 = (t < P) ? part[t] : 0;
    int v = v0;
#pragma unroll
    for (int d = 1; d < 64; d <<= 1) { int u = __shfl_up(v, d); if (lane >= d) v += u; }
    if (lane == 63) wsum[wv] = v;
    __syncthreads();
    int add = 0;
    for (int w2 = 0; w2 < wv; ++w2) add += wsum[w2];
    v += add;
    if (t < P) part[t] = v - v0;               // exclusive over partials
}

__global__ void k_scan3(int* __restrict__ row_ptr, const int* __restrict__ part, int n, int E) {
    int i = blockIdx.x * 256 + threadIdx.x;
    if (i < n) row_ptr[i] += part[blockIdx.x];
    if (i == 0) row_ptr[n] = E;
}

__global__ void k_fill(const int* __restrict__ src, const int* __restrict__ dst,
                       const int* __restrict__ row_ptr, int* __restrict__ cursor,
                       int* __restrict__ csr, int E) {
    int i = blockIdx.x * 256 + threadIdx.x;
    if (i < E) {
        int d = dst[i];
        int p = atomicAdd(&cursor[d], 1);
        csr[row_ptr[d] + p] = src[i];
    }
}
// NOTE (round-16): per-list src sort tried — FETCH unchanged, +94 us. Reverted.

// ---------------- mean aggregation: one wave/node, fp64 accumulate, 4-row unroll ----------------
template<int D>
__global__ void k_aggr(const float* __restrict__ xin, const int* __restrict__ row_ptr,
                       const int* __restrict__ csr, float* __restrict__ agg, int n) {
    int wid = (blockIdx.x * blockDim.x + threadIdx.x) >> 6;
    int lane = threadIdx.x & 63;
    if (wid >= n) return;
    constexpr int V = D / 64;
    double a0[V], a1[V], a2[V], a3[V];
#pragma unroll
    for (int i = 0; i < V; ++i) { a0[i] = 0.0; a1[i] = 0.0; a2[i] = 0.0; a3[i] = 0.0; }
    int s0 = row_ptr[wid], s1 = row_ptr[wid + 1];
    int j = s0;
    for (; j + 4 <= s1; j += 4) {
        int i0 = csr[j], i1 = csr[j + 1], i2 = csr[j + 2], i3 = csr[j + 3];
        const float* p0 = xin + (size_t)i0 * D + lane * V;
        const float* p1 = xin + (size_t)i1 * D + lane * V;
        const float* p2 = xin + (size_t)i2 * D + lane * V;
        const float* p3 = xin + (size_t)i3 * D + lane * V;
        if (V == 2) {
            float2 f0 = *(const float2*)p0, f1 = *(const float2*)p1;
            float2 f2 = *(const float2*)p2, f3 = *(const float2*)p3;
            a0[0] += (double)f0.x; a0[1] += (double)f0.y;
            a1[0] += (double)f1.x; a1[1] += (double)f1.y;
            a2[0] += (double)f2.x; a2[1] += (double)f2.y;
            a3[0] += (double)f3.x; a3[1] += (double)f3.y;
        } else {
            float4 f0 = *(const float4*)p0, f1 = *(const float4*)p1;
            float4 f2 = *(const float4*)p2, f3 = *(const float4*)p3;
            a0[0] += (double)f0.x; a0[1] += (double)f0.y; a0[2] += (double)f0.z; a0[3] += (double)f0.w;
            a1[0] += (double)f1.x; a1[1] += (double)f1.y; a1[2] += (double)f1.z; a1[3] += (double)f1.w;
            a2[0] += (double)f2.x; a2[1] += (double)f2.y; a2[2] += (double)f2.z; a2[3] += (double)f2.w;
            a3[0] += (double)f3.x; a3[1] += (double)f3.y; a3[2] += (double)f3.z; a3[3] += (double)f3.w;
        }
    }
    for (; j < s1; ++j) {
        const float* p = xin + (size_t)csr[j] * D + lane * V;
        if (V == 2) {
            float2 f = *(const float2*)p;
            a0[0] += (double)f.x; a0[1] += (double)f.y;
        } else {
            float4 f = *(const float4*)p;
            a0[0] += (double)f.x; a0[1] += (double)f.y; a0[2] += (double)f.z; a0[3] += (double)f.w;
        }
    }
    double inv = 1.0 / (double)max(s1 - s0, 1);
#pragma unroll
    for (int i = 0; i < V; ++i)
        agg[(size_t)wid * D + lane * V + i] = (float)(((a0[i] + a1[i]) + (a2[i] + a3[i])) * inv);
}

// Layer-3 fused gather: P is bf16 [n][128]; out = mean(P[neighbors]) + R (fp32, bl3
// pre-folded). Linearity swap: mean_aggr(h2)@wl3 == mean_aggr(h2@wl3); layer-3 output
// feeds NO gate, only the absmax tolerance -> bf16-class reorder is safe.
__global__ void k_aggr_badd(const unsigned short* __restrict__ Pb, const int* __restrict__ row_ptr,
                            const int* __restrict__ csr, const float* __restrict__ Rf,
                            float* __restrict__ outp, int n) {
    int wid = (blockIdx.x * blockDim.x + threadIdx.x) >> 6;
    int lane = threadIdx.x & 63;
    if (wid >= n) return;
    double a0[2], a1[2], a2[2], a3[2];
#pragma unroll
    for (int i = 0; i < 2; ++i) { a0[i] = 0.0; a1[i] = 0.0; a2[i] = 0.0; a3[i] = 0.0; }
    int s0 = row_ptr[wid], s1 = row_ptr[wid + 1];
    int j = s0;
    for (; j + 4 <= s1; j += 4) {
        int i0 = csr[j], i1 = csr[j + 1], i2 = csr[j + 2], i3 = csr[j + 3];
        unsigned u0 = *(const unsigned*)(Pb + (size_t)i0 * 128 + lane * 2);
        unsigned u1 = *(const unsigned*)(Pb + (size_t)i1 * 128 + lane * 2);
        unsigned u2 = *(const unsigned*)(Pb + (size_t)i2 * 128 + lane * 2);
        unsigned u3 = *(const unsigned*)(Pb + (size_t)i3 * 128 + lane * 2);
        a0[0] += (double)bflo(u0); a0[1] += (double)bfhi(u0);
        a1[0] += (double)bflo(u1); a1[1] += (double)bfhi(u1);
        a2[0] += (double)bflo(u2); a2[1] += (double)bfhi(u2);
        a3[0] += (double)bflo(u3); a3[1] += (double)bfhi(u3);
    }
    for (; j < s1; ++j) {
        unsigned u = *(const unsigned*)(Pb + (size_t)csr[j] * 128 + lane * 2);
        a0[0] += (double)bflo(u); a0[1] += (double)bfhi(u);
    }
    double inv = 1.0 / (double)max(s1 - s0, 1);
    float2 r = *(const float2*)(Rf + (size_t)wid * 128 + lane * 2);
    float2 o;
    o.x = (float)(((a0[0] + a1[0]) + (a2[0] + a3[0])) * inv) + r.x;
    o.y = (float)(((a0[1] + a1[1]) + (a2[1] + a3[1])) * inv) + r.y;
    *(float2*)(outp + (size_t)wid * 128 + lane * 2) = o;
}

// ---------------- gate (round-5 verbatim; fp32 weights read directly) ----------------
template<int D>
__global__ void k_gate(const float* __restrict__ agg, const float* __restrict__ wg,
                       const float* __restrict__ bg, int* __restrict__ idx,
                       int* __restrict__ ecnt, float* __restrict__ gsum, int n) {
    __shared__ float swg[D * 8];
    __shared__ int hcnt[8];
    __shared__ float red[256];
    int t = threadIdx.x;
    if (t < 8) hcnt[t] = 0;
    for (int i = t; i < D * 8; i += 256) swg[i] = wg[i];
    __syncthreads();
    int nid = blockIdx.x * 256 + t;
    float stdv = 0.f;
    if (nid < n) {
        double lg[8];
#pragma unroll
        for (int e = 0; e < 8; ++e) lg[e] = (double)bg[e];
        const float* ap = agg + (size_t)nid * D;
        for (int k = 0; k < D; k += 4) {
            float4 a = *(const float4*)(ap + k);
#pragma unroll
            for (int e = 0; e < 8; ++e) {
                lg[e] += (double)a.x * swg[(k + 0) * 8 + e] + (double)a.y * swg[(k + 1) * 8 + e]
                       + (double)a.z * swg[(k + 2) * 8 + e] + (double)a.w * swg[(k + 3) * 8 + e];
            }
        }
        double m = lg[0];
        int am = 0;
#pragma unroll
        for (int e = 1; e < 8; ++e) if (lg[e] > m) { m = lg[e]; am = e; }
        double s = 0.0, p[8];
#pragma unroll
        for (int e = 0; e < 8; ++e) { p[e] = exp(lg[e] - m); s += p[e]; }
        double invs = 1.0 / s, sq = 0.0;
#pragma unroll
        for (int e = 0; e < 8; ++e) { double q = p[e] * invs; sq += q * q; }
        stdv = (float)sqrt(fmax(sq - 0.125, 0.0) / 7.0);
        idx[nid] = am;
        atomicAdd(&hcnt[am], 1);
    }
    red[t] = stdv;
    __syncthreads();
    for (int off = 128; off > 0; off >>= 1) {
        if (t < off) red[t] += red[t + off];
        __syncthreads();
    }
    if (t == 0) atomicAdd(gsum, red[0]);
    if (t < 8 && hcnt[t] > 0) atomicAdd(&ecnt[t], hcnt[t]);
}

__global__ void k_offsets(const int* __restrict__ ecnt, int* __restrict__ eoff) {
    if (threadIdx.x == 0 && blockIdx.x == 0) {
        int s = 0;
        for (int e = 0; e < 8; ++e) { eoff[e] = s; s += ecnt[e]; }
        eoff[8] = s;
    }
}

__global__ void k_perm(const int* __restrict__ idx, const int* __restrict__ eoff,
                       int* __restrict__ ecur, int* __restrict__ perm, int n) {
    __shared__ int lcnt[8], lbase[8];
    int t = threadIdx.x;
    if (t < 8) lcnt[t] = 0;
    __syncthreads();
    int nid = blockIdx.x * 256 + t;
    int e = 0, r = 0;
    bool valid = (nid < n);
    if (valid) { e = idx[nid]; r = atomicAdd(&lcnt[e], 1); }
    __syncthreads();
    if (t < 8) lbase[t] = lcnt[t] ? atomicAdd(&ecur[t], lcnt[t]) : 0;
    __syncthreads();
    if (valid) perm[eoff[e] + lbase[e] + r] = nid;
}

// ---------------- VALU fp32 GEMM, layer 1 (compact grid; h1 bit-identical) ----------------
template<int NCOL, bool LOAD>
DEV void g_step(int g, const float* __restrict__ Bp, const float* __restrict__ at,
                float4 (&cur)[4], float (&acc)[8][4]) {
    float bx[4][4];
#pragma unroll
    for (int kk = 0; kk < 4; ++kk) {
        bx[kk][0] = cur[kk].x; bx[kk][1] = cur[kk].y;
        bx[kk][2] = cur[kk].z; bx[kk][3] = cur[kk].w;
    }
#pragma unroll
    for (int r = 0; r < 8; ++r) {
        float4 a = *(const float4*)(at + r * 68 + g * 4);   // uniform addr -> LDS broadcast
#pragma unroll
        for (int c = 0; c < 4; ++c) {
            acc[r][c] = fmaf(a.x, bx[0][c], acc[r][c]);
            acc[r][c] = fmaf(a.y, bx[1][c], acc[r][c]);
            acc[r][c] = fmaf(a.z, bx[2][c], acc[r][c]);
            acc[r][c] = fmaf(a.w, bx[3][c], acc[r][c]);
        }
    }
    if (LOAD) {
#pragma unroll
        for (int kk = 0; kk < 4; ++kk)
            cur[kk] = *(const float4*)(Bp + (size_t)(g * 4 + 8 + kk) * NCOL);
    }
}

template<int NCOL>
DEV void compute_chunk(const float* __restrict__ Bp, const float* __restrict__ at,
                       float (&acc)[8][4]) {
    float4 bA[4], bB[4];
#pragma unroll
    for (int kk = 0; kk < 4; ++kk) bA[kk] = *(const float4*)(Bp + (size_t)kk * NCOL);
#pragma unroll
    for (int kk = 0; kk < 4; ++kk) bB[kk] = *(const float4*)(Bp + (size_t)(4 + kk) * NCOL);
#pragma unroll 1
    for (int g = 0; g < 14; g += 2) {          // rolled: keep body ~2.5 KB for I$
        g_step<NCOL, true>(g, Bp, at, bA, acc);
        g_step<NCOL, true>(g + 1, Bp, at, bB, acc);
    }
    g_step<NCOL, false>(14, Bp, at, bA, acc);
    g_step<NCOL, false>(15, Bp, at, bB, acc);
}

template<int DIN, int NCOL, bool RELU>
__global__ __launch_bounds__(256, 4) void k_gemm_f32(
    const float* __restrict__ agg, const float* __restrict__ a2,
    const float* __restrict__ B1, const float* __restrict__ B2,
    const float* __restrict__ bias,
    const int* __restrict__ perm, const int* __restrict__ eoff,
    float* __restrict__ outp, int n) {
    static_assert(DIN == 128 && NCOL == 256, "layer-1 geometry");
    __shared__ float a_tile[2][4 * 8 * 68];
    __shared__ int rows[32];
    int t = threadIdx.x;
    int rs = blockIdx.x * 32;
    if (rs >= n) return;
    int nrows = min(32, n - rs);
    if (t < 32) rows[t] = perm[rs + min(t, nrows - 1)];
    __syncthreads();                            // the only barrier in this kernel

    int e0 = 0, e1 = 0;
    int last = rs + nrows - 1;
#pragma unroll
    for (int e = 1; e < 8; ++e) {
        int v = eoff[e];
        if (v <= rs) e0 = e;
        if (v <= last) e1 = e;
    }
    int ne = e1 - e0 + 1;
    int nchunks = 2 * ne + 2;

    int lane = t & 63, rg = t >> 6;
    int cols = lane * 4;
    int srow = lane >> 3;                       // 0..7 within wave
    int sk = (lane & 7) * 8;                    // 0..56
    int gpos = rs + rg * 8 + srow;              // global perm position of my staged row
    int myrow = rows[rg * 8 + srow];
    float* stc = &a_tile[0][rg * 544 + srow * 68 + sk];
    float* stn = &a_tile[1][rg * 544 + srow * 68 + sk];
    const float* atc = &a_tile[0][rg * 544];
    const float* atn = &a_tile[1][rg * 544];

    float acc[8][4];
#pragma unroll
    for (int r = 0; r < 8; ++r) { acc[r][0] = 0.f; acc[r][1] = 0.f; acc[r][2] = 0.f; acc[r][3] = 0.f; }

    auto params = [&](int c, const float*& ap, const float*& Bp, float& m) {
        int half = c & 1;
        if (c < 2 * ne) {
            int e = e0 + (c >> 1);
            ap = agg + (size_t)myrow * DIN + sk + half * 64;
            Bp = B1 + (size_t)e * DIN * NCOL + (size_t)half * 64 * NCOL + cols;
            m = (gpos >= eoff[e] && gpos < eoff[e + 1]) ? 1.f : 0.f;
        } else {
            ap = a2 + (size_t)myrow * DIN + sk + half * 64;
            Bp = B2 + (size_t)half * 64 * NCOL + cols;
            m = 1.f;
        }
    };

    const float* ap; const float* Bp; float m;
    params(0, ap, Bp, m);
    float4 p0 = *(const float4*)ap, p1 = *(const float4*)(ap + 4);
#pragma unroll 1
    for (int c = 0; c < nchunks; ++c) {
        float4 s0 = p0, s1 = p1;
        s0.x *= m; s0.y *= m; s0.z *= m; s0.w *= m;
        s1.x *= m; s1.y *= m; s1.z *= m; s1.w *= m;
        *(float4*)stc = s0; *(float4*)(stc + 4) = s1;
        const float* Bcur = Bp;
        if (c + 1 < nchunks) {                  // prefetch next chunk's A (hidden under compute)
            params(c + 1, ap, Bp, m);
            p0 = *(const float4*)ap; p1 = *(const float4*)(ap + 4);
        }
        compute_chunk<NCOL>(Bcur, atc, acc);
        float* ts = stc; stc = stn; stn = ts;
        const float* ta = atc; atc = atn; atn = ta;
    }

#pragma unroll
    for (int r = 0; r < 8; ++r) {
        int rr = rg * 8 + r;
        if (rr < nrows) {
            int gp = rs + rr;
            int er = e0;
            for (int e = e0 + 1; e <= e1; ++e) if (eoff[e] <= gp) er = e;
            float4 bb = *(const float4*)(bias + er * NCOL + cols);
            int gr = rows[rr];
            float v0 = acc[r][0] + bb.x, v1 = acc[r][1] + bb.y;
            float v2 = acc[r][2] + bb.z, v3 = acc[r][3] + bb.w;
            if (RELU) { v0 = fmaxf(v0, 0.f); v1 = fmaxf(v1, 0.f); v2 = fmaxf(v2, 0.f); v3 = fmaxf(v3, 0.f); }
            *(float4*)(outp + (size_t)gr * NCOL + cols) = make_float4(v0, v1, v2, v3);
        }
    }
}

// ---------------- MFMA GEMM core step. MODE 0: fp32 A -> f2bf in LDS (amask=false
// stages zeros -> acc+0 exact). MODE 2: A already bf16, direct stage. ----------------
template<int DIN, int MODE, int CT>
DEV void gemm_span(const void* __restrict__ Asrc, const unsigned short* __restrict__ BT,
                   short (*Ah)[40], short (*Bs)[40],
                   const int* rows, f32x4 (&acc)[4][CT], int t, int lane, int w, bool amask) {
    int q = lane >> 4, m16 = lane & 15;
    int r = t >> 2, part = t & 3;
    for (int kc = 0; kc < DIN; kc += 32) {
        __syncthreads();
        if (!amask) {
            *(uint4*)&Ah[r][part * 8] = make_uint4(0u, 0u, 0u, 0u);
        } else if (MODE == 2) {
            *(uint4*)&Ah[r][part * 8] =
                *(const uint4*)((const unsigned short*)Asrc + (size_t)rows[r] * DIN + kc + part * 8);
        } else {
            const float* pf = (const float*)Asrc + (size_t)rows[r] * DIN + kc + part * 8;
            float4 p0 = *(const float4*)pf, p1 = *(const float4*)(pf + 4);
            float va[8] = { p0.x, p0.y, p0.z, p0.w, p1.x, p1.y, p1.z, p1.w };
            short8 h;
#pragma unroll
            for (int j = 0; j < 8; ++j) h[j] = (short)f2bf(va[j]);
            *(short8*)&Ah[r][part * 8] = h;
        }
#pragma unroll
        for (int j = 0; j < CT; ++j) {
            int c = t + 256 * j;
            int nn = c >> 2, pp = c & 3;
            *(uint4*)&Bs[nn][pp * 8] = *(const uint4*)(BT + (size_t)nn * DIN + kc + pp * 8);
        }
        __syncthreads();
        short8 af[4], bfr[CT];
#pragma unroll
        for (int rt = 0; rt < 4; ++rt) af[rt] = *(short8*)&Ah[rt * 16 + m16][q * 8];
#pragma unroll
        for (int ct = 0; ct < CT; ++ct) bfr[ct] = *(short8*)&Bs[w * CT * 16 + ct * 16 + m16][q * 8];
#pragma unroll
        for (int rt = 0; rt < 4; ++rt)
#pragma unroll
            for (int ct = 0; ct < CT; ++ct)
                acc[rt][ct] = __builtin_amdgcn_mfma_f32_16x16x32_bf16(af[rt], bfr[ct], acc[rt][ct], 0, 0, 0);
    }
}

// ---------------- layer-2 MoE MFMA GEMM, COMPACT GRID (round-17) ----------------
// Exactly ceil(N/64) blocks over the global permuted row space (was dim3(GB,8) with
// 87.5% chaff -> dispatch dilution, the same disease fixed on layer 1 in round-12).
// Boundary blocks (<=7 of 782) run one pass per expert present with A=0 staged for
// out-of-segment rows: MFMA acc+0*B = acc exactly, and each row's value-changing
// accumulation order (own expert K 0..255, then root K 0..255) is unchanged ->
// h2 bit-identical, gate-free downstream anyway.
template<int DIN>
__global__ __launch_bounds__(256) void k_gemm_moe(
    const float* __restrict__ agg, const float* __restrict__ h1,
    const unsigned short* __restrict__ BeT, const unsigned short* __restrict__ BrT,
    const float* __restrict__ bias,
    const int* __restrict__ perm, const int* __restrict__ eoff,
    unsigned short* __restrict__ outp, int n) {
    constexpr int CT = 4;
    constexpr int NCOL = CT * 64;
    __shared__ short Ah[64][40];
    __shared__ short Bs[NCOL][40];
    __shared__ int rows[64];
    int t = threadIdx.x;
    int lane = t & 63, w = t >> 6;
    int rs = blockIdx.x * 64;
    if (rs >= n) return;
    int nrows = min(64, n - rs);
    if (t < 64) rows[t] = perm[rs + min(t, nrows - 1)];
    __syncthreads();

    int e0 = 0, e1 = 0;
    int last = rs + nrows - 1;
#pragma unroll
    for (int e = 1; e < 8; ++e) {
        int v = eoff[e];
        if (v <= rs) e0 = e;
        if (v <= last) e1 = e;
    }

    f32x4 acc[4][CT];
#pragma unroll
    for (int rt = 0; rt < 4; ++rt)
#pragma unroll
        for (int ct = 0; ct < CT; ++ct) acc[rt][ct] = (f32x4)(0.f);

    int r = t >> 2;
    int gposr = rs + r;                          // staged row's perm position
    for (int e = e0; e <= e1; ++e) {
        bool inseg = (gposr >= eoff[e] && gposr < eoff[e + 1]);
        gemm_span<DIN, 0, CT>(agg, BeT + (size_t)e * DIN * NCOL, Ah, Bs, rows, acc,
                              t, lane, w, inseg);
    }
    gemm_span<DIN, 0, CT>(h1, BrT, Ah, Bs, rows, acc, t, lane, w, true);

    int q = lane >> 4, m16 = lane & 15;
#pragma unroll
    for (int ct = 0; ct < CT; ++ct) {
        int col = w * CT * 16 + ct * 16 + m16;
#pragma unroll
        for (int rt = 0; rt < 4; ++rt)
#pragma unroll
            for (int i = 0; i < 4; ++i) {
                int rr = rt * 16 + q * 4 + i;
                if (rr < nrows) {
                    int gp = rs + rr;
                    int er = e0;
                    for (int e = e0 + 1; e <= e1; ++e) if (eoff[e] <= gp) er = e;
                    float v = acc[rt][ct][i] + bias[er * NCOL + col];
                    v = fmaxf(v, 0.f);           // relu
                    outp[(size_t)rows[rr] * NCOL + col] = f2bf(v);
                }
            }
    }
}

// ---------------- layer-3 GEMM (no experts). OUTMODE 2: split store:
// cols<128 -> bf16 outp (stride 128), cols>=128 -> fp32 outp2 (stride 128). ----------------
template<int DIN, int M0, int CT, int OUTMODE>
__global__ __launch_bounds__(256) void k_gemm(
    const void* __restrict__ A0,
    const unsigned short* __restrict__ B0T,
    const float* __restrict__ bias,
    void* __restrict__ outp, void* __restrict__ outp2, int n) {
    constexpr int NCOL = CT * 64;
    __shared__ short Ah[64][40];
    __shared__ short Bs[NCOL][40];
    __shared__ int rows[64];
    int t = threadIdx.x;
    int lane = t & 63, w = t >> 6;
    int rs = blockIdx.x * 64;
    if (rs >= n) return;
    int nrows = min(64, n - rs);
    if (t < 64) rows[t] = rs + min(t, nrows - 1);
    __syncthreads();
    f32x4 acc[4][CT];
#pragma unroll
    for (int rt = 0; rt < 4; ++rt)
#pragma unroll
        for (int ct = 0; ct < CT; ++ct) acc[rt][ct] = (f32x4)(0.f);

    gemm_span<DIN, M0, CT>(A0, B0T, Ah, Bs, rows, acc, t, lane, w, true);

    int q = lane >> 4, m16 = lane & 15;
#pragma unroll
    for (int ct = 0; ct < CT; ++ct) {
        int col = w * CT * 16 + ct * 16 + m16;
        float bv = bias[col];
#pragma unroll
        for (int rt = 0; rt < 4; ++rt)
#pragma unroll
            for (int i = 0; i < 4; ++i) {
                int rr = rt * 16 + q * 4 + i;
                if (rr < nrows) {
                    int gr = rows[rr];
                    float v = acc[rt][ct][i] + bv;
                    if (OUTMODE == 1) ((unsigned short*)outp)[(size_t)gr * NCOL + col] = f2bf(v);
                    else if (OUTMODE == 0) ((float*)outp)[(size_t)gr * NCOL + col] = v;
                    else {
                        if (col < 128) ((unsigned short*)outp)[(size_t)gr * 128 + col] = f2bf(v);
                        else           ((float*)outp2)[(size_t)gr * 128 + (col - 128)] = v;
                    }
                }
            }
    }
}

__global__ void k_final(const float* __restrict__ gsum, float* __restrict__ outf) {
    if (threadIdx.x == 0 && blockIdx.x == 0) {
        float g = (gsum[0] + gsum[1]) * (0.5f / 50000.0f);
        outf[(size_t)50000 * 128] = g;   // output buffer is fp32
    }
}

extern "C" void kernel_launch(void* const* d_in, const int* in_sizes, int n_in,
                              void* d_out, int out_size, void* d_ws, size_t ws_size,
                              hipStream_t stream) {
    constexpr int N = 50000, E = 800000;
    const float* x   = (const float*)d_in[0];
    const int* ei    = (const int*)d_in[1];
    const float* wg1 = (const float*)d_in[2];
    const float* bg1 = (const float*)d_in[3];
    const float* we1 = (const float*)d_in[4];
    const float* be1 = (const float*)d_in[5];
    const float* wr1 = (const float*)d_in[6];
    const float* wg2 = (const float*)d_in[7];
    const float* bg2 = (const float*)d_in[8];
    const float* we2 = (const float*)d_in[9];
    const float* be2 = (const float*)d_in[10];
    const float* wr2 = (const float*)d_in[11];
    const float* wl3 = (const float*)d_in[12];
    const float* bl3 = (const float*)d_in[13];
    const float* wr3 = (const float*)d_in[14];

    // ---- workspace layout ----
    int* ip = (int*)d_ws;
    int* deg = ip;            ip += N;
    int* cursor = ip;         ip += N;
    int* ecnt = ip;           ip += 16;
    int* ecur = ip;           ip += 16;
    float* gsum = (float*)ip; ip += 2;
    int* flags = ip;          ip += 2;
    float* bias3 = (float*)ip; ip += 256;
    int* row_ptr = ip;        ip += N + 1;
    int* csr = ip;            ip += E;
    int* idxb = ip;           ip += N;
    int* permb = ip;          ip += N;
    int* eoff = ip;           ip += 18;
    int* part = ip;           ip += 256;
    int* src32 = ip;          ip += E;
    int* dst32 = ip;          ip += E;
    size_t off = (size_t)((char*)ip - (char*)d_ws);
    off = (off + 255) & ~(size_t)255;
    float* fp = (float*)((char*)d_ws + off);
    float* agg = fp; fp += (size_t)N * 256;            // fp32 agg (layers 1-2)
    float* h1  = fp; fp += (size_t)N * 256;            // fp32 h1 (gate-2 critical)
    unsigned short* wp = (unsigned short*)fp;
    unsigned short* h2b  = wp; wp += (size_t)N * 256;  // bf16 h2 (gate-free)
    unsigned short* we2T = wp; wp += 8 * 256 * 256;    // bf16 B^T [n][k]
    unsigned short* wr2T = wp; wp += 256 * 256;
    unsigned short* wl3T = wp; wp += 256 * 128;        // + wr3T adjacent = [256][256] B^T
    unsigned short* wr3T = wp; wp += 256 * 128;
    // layer-3 swap buffers alias dead regions (agg/h1 unused after layer-2 gemm)
    unsigned short* Pb = (unsigned short*)h1;          // bf16 [N][128] = h2b @ wl3
    float* Rf = agg;                                   // fp32 [N][128] = h2b @ wr3 + bl3

    hipMemsetAsync(d_ws, 0, (size_t)(2 * N + 36) * 4, stream);

    k_detect<<<1, 64, 0, stream>>>(ei, flags);
    k_cvt_idx<<<(E + 255) / 256, 256, 0, stream>>>(ei, src32, dst32, deg, E, flags);

    // fused transpose+narrow to bf16 B^T [n][k] (layers 2/3)
    k_transpose_nb<<<dim3(8, 8, 8), 256, 0, stream>>>(we2, we2T, 256, 256);
    k_transpose_nb<<<dim3(8, 8, 1), 256, 0, stream>>>(wr2, wr2T, 256, 256);
    k_transpose_nb<<<dim3(4, 8, 1), 256, 0, stream>>>(wl3, wl3T, 256, 128);
    k_transpose_nb<<<dim3(4, 8, 1), 256, 0, stream>>>(wr3, wr3T, 256, 128);
    k_bias3<<<1, 256, 0, stream>>>(bl3, bias3);

    // CSR (degree fused into k_cvt_idx)
    constexpr int NB = (N + 255) / 256;
    constexpr int WB = (N + 3) / 4;
    k_scan1<<<NB, 256, 0, stream>>>(deg, row_ptr, part, N);
    k_scan2<<<1, 256, 0, stream>>>(part, NB);
    k_scan3<<<NB, 256, 0, stream>>>(row_ptr, part, N, E);
    k_fill<<<(E + 255) / 256, 256, 0, stream>>>(src32, dst32, row_ptr, cursor, csr, E);

    constexpr int GB = (N + 63) / 64;      // 64-row tiles (MFMA layers 2/3, compact)
    constexpr int GB32 = (N + 31) / 32;    // 32-row tiles (VALU layer 1, compact)
    // ---- layer 1: 128 -> 256, MoE + root(x), relu — VALU fp32 (h1 bit-identical) ----
    k_aggr<128><<<WB, 256, 0, stream>>>(x, row_ptr, csr, agg, N);
    k_gate<128><<<NB, 256, 0, stream>>>(agg, wg1, bg1, idxb, ecnt, gsum, N);
    k_offsets<<<1, 1, 0, stream>>>(ecnt, eoff);
    k_perm<<<NB, 256, 0, stream>>>(idxb, eoff, ecur, permb, N);
    k_gemm_f32<128, 256, true><<<dim3(GB32), 256, 0, stream>>>(
        agg, x, we1, wr1, be1, permb, eoff, h1, N);

    // ---- layer 2: 256 -> 256, MoE + root(h1), relu — compact-grid MFMA; bf16 h2b ----
    k_aggr<256><<<WB, 256, 0, stream>>>(h1, row_ptr, csr, agg, N);
    k_gate<256><<<NB, 256, 0, stream>>>(agg, wg2, bg2, idxb, ecnt + 8, gsum + 1, N);
    k_offsets<<<1, 1, 0, stream>>>(ecnt + 8, eoff + 9);
    k_perm<<<NB, 256, 0, stream>>>(idxb, eoff + 9, ecur + 8, permb, N);
    k_gemm_moe<256><<<dim3(GB), 256, 0, stream>>>(
        agg, h1, we2T, wr2T, be2, permb, eoff + 9, h2b, N);

    // ---- layer 3 (linearity swap): [P|R] = h2b @ [wl3|wr3]; out = mean_aggr(P) + R ----
    k_gemm<256, 2, 4, 2><<<dim3(GB), 256, 0, stream>>>(
        h2b, wl3T, bias3, Pb, Rf, N);
    k_aggr_badd<<<WB, 256, 0, stream>>>(Pb, row_ptr, csr, Rf, (float*)d_out, N);

    k_final<<<1, 1, 0, stream>>>(gsum, (float*)d_out);
}

// Round 8
// 654.836 us; speedup vs baseline: 1.0272x; 1.0272x over previous
//
#include <hip/hip_runtime.h>
#include <hip/hip_bf16.h>
#include <stdint.h>

#define DEV static __device__ __forceinline__

typedef __attribute__((ext_vector_type(8))) short short8;   // 8 bf16 (4 VGPRs)
typedef __attribute__((ext_vector_type(4))) float f32x4;    // MFMA accumulator

DEV float bf2f(unsigned short u) { return __uint_as_float(((unsigned)u) << 16); }
DEV float bflo(unsigned u) { return __uint_as_float(u << 16); }
DEV float bfhi(unsigned u) { return __uint_as_float(u & 0xffff0000u); }
DEV unsigned short f2bf(float f) {
    unsigned u = __float_as_uint(f);
    u += 0x7fff + ((u >> 16) & 1);   // RNE
    return (unsigned short)(u >> 16);
}

// ---------------- edge_index width detection (int64 vs int32) ----------------
__global__ void k_detect(const int* __restrict__ ei, int* __restrict__ flags) {
    if (threadIdx.x == 0 && blockIdx.x == 0) {
        int zeros = 0;
        for (int i = 0; i < 128; ++i) if (ei[2 * i + 1] == 0) ++zeros;
        flags[1] = (zeros >= 64) ? 1 : 0;
    }
}

// fused: index narrow + degree count (saves a separate 800k-element pass)
__global__ void k_cvt_idx(const int* __restrict__ ei, int* __restrict__ src32,
                          int* __restrict__ dst32, int* __restrict__ deg,
                          int E, const int* __restrict__ flags) {
    int i = blockIdx.x * 256 + threadIdx.x;
    if (i >= E) return;
    int s, d;
    if (flags[1]) { s = ei[2 * i]; d = ei[2 * E + 2 * i]; }
    else          { s = ei[i];     d = ei[E + i]; }
    src32[i] = s; dst32[i] = d;
    atomicAdd(&deg[d], 1);
}

// ---------------- fused transpose+narrow: fp32 in[r][c] -> bf16 out[c][r] ----------------
__global__ void k_transpose_nb(const float* __restrict__ in, unsigned short* __restrict__ out,
                               int R, int C) {
    __shared__ unsigned short tile[32][33];
    int tx = threadIdx.x & 31, ty = threadIdx.x >> 5;   // 256 threads = 32x8
    size_t mat = (size_t)blockIdx.z * R * C;
    int r0 = blockIdx.y * 32, c0 = blockIdx.x * 32;
#pragma unroll
    for (int j = 0; j < 32; j += 8)
        tile[ty + j][tx] = f2bf(in[mat + (size_t)(r0 + ty + j) * C + c0 + tx]);
    __syncthreads();
#pragma unroll
    for (int j = 0; j < 32; j += 8)
        out[mat + (size_t)(c0 + ty + j) * R + r0 + tx] = tile[tx][ty + j];
}

// bias for the fused layer-3 GEMM: cols 0..127 (P half) get 0, cols 128..255 get bl3
__global__ void k_bias3(const float* __restrict__ bl3, float* __restrict__ bias3) {
    int t = threadIdx.x;
    bias3[t] = (t < 128) ? 0.f : bl3[t - 128];
}

// ---------------- CSR build: degree (fused above) -> 3-phase shfl scan -> fill ----------------
__global__ void k_scan1(const int* __restrict__ deg, int* __restrict__ row_ptr,
                        int* __restrict__ part, int n) {
    __shared__ int wsum[4];
    int t = threadIdx.x, lane = t & 63, wv = t >> 6;
    int i = blockIdx.x * 256 + t;
    int v0 = (i < n) ? deg[i] : 0;
    int v = v0;
#pragma unroll
    for (int d = 1; d < 64; d <<= 1) { int u = __shfl_up(v, d); if (lane >= d) v += u; }
    if (lane == 63) wsum[wv] = v;
    __syncthreads();
    int add = 0;
    for (int w2 = 0; w2 < wv; ++w2) add += wsum[w2];
    v += add;
    if (i < n) row_ptr[i] = v - v0;            // block-local exclusive
    if (t == 255) part[blockIdx.x] = v;        // block total
}

__global__ void k_scan2(int* __restrict__ part, int P) {
    __shared__ int wsum[4];
    int t = threadIdx.x, lane = t & 63, wv = t >> 6;
    int v0 = (t < P) ? part[t] : 0;
    int v = v0;
#pragma unroll
    for (int d = 1; d < 64; d <<= 1) { int u = __shfl_up(v, d); if (lane >= d) v += u; }
    if (lane == 63) wsum[wv] = v;
    __syncthreads();
    int add = 0;
    for (int w2 = 0; w2 < wv; ++w2) add += wsum[w2];
    v += add;
    if (t < P) part[t] = v - v0;               // exclusive over partials
}

__global__ void k_scan3(int* __restrict__ row_ptr, const int* __restrict__ part, int n, int E) {
    int i = blockIdx.x * 256 + threadIdx.x;
    if (i < n) row_ptr[i] += part[blockIdx.x];
    if (i == 0) row_ptr[n] = E;
}

__global__ void k_fill(const int* __restrict__ src, const int* __restrict__ dst,
                       const int* __restrict__ row_ptr, int* __restrict__ cursor,
                       int* __restrict__ csr, int E) {
    int i = blockIdx.x * 256 + threadIdx.x;
    if (i < E) {
        int d = dst[i];
        int p = atomicAdd(&cursor[d], 1);
        csr[row_ptr[d] + p] = src[i];
    }
}
// NOTE (round-16): per-list src sort tried — FETCH unchanged, +94 us. Reverted.
// NOTE (round-17): compact-grid MFMA MoE GEMM tried — +18 us. Chaff blocks in
// dim3(GB,8) exit before any barrier; dispatch drain is ~free. Reverted.

// ---------------- mean aggregation: one wave/node, fp64 accumulate ----------------
// Round-18: 8-row unroll (was 4). Latency-bound signature (VALUBusy 20%, occ 53%,
// 3.8 TB/s): only 4 KB of loads in flight per wave. 8 rows doubles outstanding
// traffic. Numerics: only changes the fp64 summation tree (~1e-16 class, below the
// gate argmax cliff per round-4/5 bracketing). launch_bounds(256,2): 256-VGPR cap,
// no spill at ~110 VGPR (D=256).
template<int D>
__global__ __launch_bounds__(256, 2) void k_aggr(
    const float* __restrict__ xin, const int* __restrict__ row_ptr,
    const int* __restrict__ csr, float* __restrict__ agg, int n) {
    int wid = (blockIdx.x * blockDim.x + threadIdx.x) >> 6;
    int lane = threadIdx.x & 63;
    if (wid >= n) return;
    constexpr int V = D / 64;
    double ac[8][V];
#pragma unroll
    for (int r = 0; r < 8; ++r)
#pragma unroll
        for (int i = 0; i < V; ++i) ac[r][i] = 0.0;
    int s0 = row_ptr[wid], s1 = row_ptr[wid + 1];
    int j = s0;
    for (; j + 8 <= s1; j += 8) {
        const float* p[8];
#pragma unroll
        for (int r = 0; r < 8; ++r) p[r] = xin + (size_t)csr[j + r] * D + lane * V;
        if (V == 2) {
            float2 f[8];
#pragma unroll
            for (int r = 0; r < 8; ++r) f[r] = *(const float2*)p[r];
#pragma unroll
            for (int r = 0; r < 8; ++r) { ac[r][0] += (double)f[r].x; ac[r][1] += (double)f[r].y; }
        } else {
            float4 f[8];
#pragma unroll
            for (int r = 0; r < 8; ++r) f[r] = *(const float4*)p[r];
#pragma unroll
            for (int r = 0; r < 8; ++r) {
                ac[r][0] += (double)f[r].x; ac[r][1] += (double)f[r].y;
                ac[r][2] += (double)f[r].z; ac[r][3] += (double)f[r].w;
            }
        }
    }
    for (; j + 4 <= s1; j += 4) {
        const float* p[4];
#pragma unroll
        for (int r = 0; r < 4; ++r) p[r] = xin + (size_t)csr[j + r] * D + lane * V;
        if (V == 2) {
            float2 f[4];
#pragma unroll
            for (int r = 0; r < 4; ++r) f[r] = *(const float2*)p[r];
#pragma unroll
            for (int r = 0; r < 4; ++r) { ac[r][0] += (double)f[r].x; ac[r][1] += (double)f[r].y; }
        } else {
            float4 f[4];
#pragma unroll
            for (int r = 0; r < 4; ++r) f[r] = *(const float4*)p[r];
#pragma unroll
            for (int r = 0; r < 4; ++r) {
                ac[r][0] += (double)f[r].x; ac[r][1] += (double)f[r].y;
                ac[r][2] += (double)f[r].z; ac[r][3] += (double)f[r].w;
            }
        }
    }
    for (; j < s1; ++j) {
        const float* p = xin + (size_t)csr[j] * D + lane * V;
        if (V == 2) {
            float2 f = *(const float2*)p;
            ac[0][0] += (double)f.x; ac[0][1] += (double)f.y;
        } else {
            float4 f = *(const float4*)p;
            ac[0][0] += (double)f.x; ac[0][1] += (double)f.y;
            ac[0][2] += (double)f.z; ac[0][3] += (double)f.w;
        }
    }
    double inv = 1.0 / (double)max(s1 - s0, 1);
#pragma unroll
    for (int i = 0; i < V; ++i) {
        double s = ((ac[0][i] + ac[1][i]) + (ac[2][i] + ac[3][i]))
                 + ((ac[4][i] + ac[5][i]) + (ac[6][i] + ac[7][i]));
        agg[(size_t)wid * D + lane * V + i] = (float)(s * inv);
    }
}

// Layer-3 fused gather (8-row unroll): P is bf16 [n][128]; out = mean(P[nbrs]) + R.
__global__ __launch_bounds__(256, 2) void k_aggr_badd(
    const unsigned short* __restrict__ Pb, const int* __restrict__ row_ptr,
    const int* __restrict__ csr, const float* __restrict__ Rf,
    float* __restrict__ outp, int n) {
    int wid = (blockIdx.x * blockDim.x + threadIdx.x) >> 6;
    int lane = threadIdx.x & 63;
    if (wid >= n) return;
    double ac[8][2];
#pragma unroll
    for (int r = 0; r < 8; ++r) { ac[r][0] = 0.0; ac[r][1] = 0.0; }
    int s0 = row_ptr[wid], s1 = row_ptr[wid + 1];
    int j = s0;
    for (; j + 8 <= s1; j += 8) {
        unsigned u[8];
#pragma unroll
        for (int r = 0; r < 8; ++r) u[r] = *(const unsigned*)(Pb + (size_t)csr[j + r] * 128 + lane * 2);
#pragma unroll
        for (int r = 0; r < 8; ++r) { ac[r][0] += (double)bflo(u[r]); ac[r][1] += (double)bfhi(u[r]); }
    }
    for (; j + 4 <= s1; j += 4) {
        unsigned u[4];
#pragma unroll
        for (int r = 0; r < 4; ++r) u[r] = *(const unsigned*)(Pb + (size_t)csr[j + r] * 128 + lane * 2);
#pragma unroll
        for (int r = 0; r < 4; ++r) { ac[r][0] += (double)bflo(u[r]); ac[r][1] += (double)bfhi(u[r]); }
    }
    for (; j < s1; ++j) {
        unsigned u = *(const unsigned*)(Pb + (size_t)csr[j] * 128 + lane * 2);
        ac[0][0] += (double)bflo(u); ac[0][1] += (double)bfhi(u);
    }
    double inv = 1.0 / (double)max(s1 - s0, 1);
    float2 r2 = *(const float2*)(Rf + (size_t)wid * 128 + lane * 2);
    float2 o;
    o.x = (float)((((ac[0][0] + ac[1][0]) + (ac[2][0] + ac[3][0]))
                 + ((ac[4][0] + ac[5][0]) + (ac[6][0] + ac[7][0]))) * inv) + r2.x;
    o.y = (float)((((ac[0][1] + ac[1][1]) + (ac[2][1] + ac[3][1]))
                 + ((ac[4][1] + ac[5][1]) + (ac[6][1] + ac[7][1]))) * inv) + r2.y;
    *(float2*)(outp + (size_t)wid * 128 + lane * 2) = o;
}

// ---------------- gate (round-5 verbatim; fp32 weights read directly) ----------------
template<int D>
__global__ void k_gate(const float* __restrict__ agg, const float* __restrict__ wg,
                       const float* __restrict__ bg, int* __restrict__ idx,
                       int* __restrict__ ecnt, float* __restrict__ gsum, int n) {
    __shared__ float swg[D * 8];
    __shared__ int hcnt[8];
    __shared__ float red[256];
    int t = threadIdx.x;
    if (t < 8) hcnt[t] = 0;
    for (int i = t; i < D * 8; i += 256) swg[i] = wg[i];
    __syncthreads();
    int nid = blockIdx.x * 256 + t;
    float stdv = 0.f;
    if (nid < n) {
        double lg[8];
#pragma unroll
        for (int e = 0; e < 8; ++e) lg[e] = (double)bg[e];
        const float* ap = agg + (size_t)nid * D;
        for (int k = 0; k < D; k += 4) {
            float4 a = *(const float4*)(ap + k);
#pragma unroll
            for (int e = 0; e < 8; ++e) {
                lg[e] += (double)a.x * swg[(k + 0) * 8 + e] + (double)a.y * swg[(k + 1) * 8 + e]
                       + (double)a.z * swg[(k + 2) * 8 + e] + (double)a.w * swg[(k + 3) * 8 + e];
            }
        }
        double m = lg[0];
        int am = 0;
#pragma unroll
        for (int e = 1; e < 8; ++e) if (lg[e] > m) { m = lg[e]; am = e; }
        double s = 0.0, p[8];
#pragma unroll
        for (int e = 0; e < 8; ++e) { p[e] = exp(lg[e] - m); s += p[e]; }
        double invs = 1.0 / s, sq = 0.0;
#pragma unroll
        for (int e = 0; e < 8; ++e) { double q = p[e] * invs; sq += q * q; }
        stdv = (float)sqrt(fmax(sq - 0.125, 0.0) / 7.0);
        idx[nid] = am;
        atomicAdd(&hcnt[am], 1);
    }
    red[t] = stdv;
    __syncthreads();
    for (int off = 128; off > 0; off >>= 1) {
        if (t < off) red[t] += red[t + off];
        __syncthreads();
    }
    if (t == 0) atomicAdd(gsum, red[0]);
    if (t < 8 && hcnt[t] > 0) atomicAdd(&ecnt[t], hcnt[t]);
}

__global__ void k_offsets(const int* __restrict__ ecnt, int* __restrict__ eoff) {
    if (threadIdx.x == 0 && blockIdx.x == 0) {
        int s = 0;
        for (int e = 0; e < 8; ++e) { eoff[e] = s; s += ecnt[e]; }
        eoff[8] = s;
    }
}

__global__ void k_perm(const int* __restrict__ idx, const int* __restrict__ eoff,
                       int* __restrict__ ecur, int* __restrict__ perm, int n) {
    __shared__ int lcnt[8], lbase[8];
    int t = threadIdx.x;
    if (t < 8) lcnt[t] = 0;
    __syncthreads();
    int nid = blockIdx.x * 256 + t;
    int e = 0, r = 0;
    bool valid = (nid < n);
    if (valid) { e = idx[nid]; r = atomicAdd(&lcnt[e], 1); }
    __syncthreads();
    if (t < 8) lbase[t] = lcnt[t] ? atomicAdd(&ecur[t], lcnt[t]) : 0;
    __syncthreads();
    if (valid) perm[eoff[e] + lbase[e] + r] = nid;
}

// ---------------- VALU fp32 GEMM, layer 1 (compact grid; h1 bit-identical) ----------------
template<int NCOL, bool LOAD>
DEV void g_step(int g, const float* __restrict__ Bp, const float* __restrict__ at,
                float4 (&cur)[4], float (&acc)[8][4]) {
    float bx[4][4];
#pragma unroll
    for (int kk = 0; kk < 4; ++kk) {
        bx[kk][0] = cur[kk].x; bx[kk][1] = cur[kk].y;
        bx[kk][2] = cur[kk].z; bx[kk][3] = cur[kk].w;
    }
#pragma unroll
    for (int r = 0; r < 8; ++r) {
        float4 a = *(const float4*)(at + r * 68 + g * 4);   // uniform addr -> LDS broadcast
#pragma unroll
        for (int c = 0; c < 4; ++c) {
            acc[r][c] = fmaf(a.x, bx[0][c], acc[r][c]);
            acc[r][c] = fmaf(a.y, bx[1][c], acc[r][c]);
            acc[r][c] = fmaf(a.z, bx[2][c], acc[r][c]);
            acc[r][c] = fmaf(a.w, bx[3][c], acc[r][c]);
        }
    }
    if (LOAD) {
#pragma unroll
        for (int kk = 0; kk < 4; ++kk)
            cur[kk] = *(const float4*)(Bp + (size_t)(g * 4 + 8 + kk) * NCOL);
    }
}

template<int NCOL>
DEV void compute_chunk(const float* __restrict__ Bp, const float* __restrict__ at,
                       float (&acc)[8][4]) {
    float4 bA[4], bB[4];
#pragma unroll
    for (int kk = 0; kk < 4; ++kk) bA[kk] = *(const float4*)(Bp + (size_t)kk * NCOL);
#pragma unroll
    for (int kk = 0; kk < 4; ++kk) bB[kk] = *(const float4*)(Bp + (size_t)(4 + kk) * NCOL);
#pragma unroll 1
    for (int g = 0; g < 14; g += 2) {          // rolled: keep body ~2.5 KB for I$
        g_step<NCOL, true>(g, Bp, at, bA, acc);
        g_step<NCOL, true>(g + 1, Bp, at, bB, acc);
    }
    g_step<NCOL, false>(14, Bp, at, bA, acc);
    g_step<NCOL, false>(15, Bp, at, bB, acc);
}

template<int DIN, int NCOL, bool RELU>
__global__ __launch_bounds__(256, 4) void k_gemm_f32(
    const float* __restrict__ agg, const float* __restrict__ a2,
    const float* __restrict__ B1, const float* __restrict__ B2,
    const float* __restrict__ bias,
    const int* __restrict__ perm, const int* __restrict__ eoff,
    float* __restrict__ outp, int n) {
    static_assert(DIN == 128 && NCOL == 256, "layer-1 geometry");
    __shared__ float a_tile[2][4 * 8 * 68];
    __shared__ int rows[32];
    int t = threadIdx.x;
    int rs = blockIdx.x * 32;
    if (rs >= n) return;
    int nrows = min(32, n - rs);
    if (t < 32) rows[t] = perm[rs + min(t, nrows - 1)];
    __syncthreads();                            // the only barrier in this kernel

    int e0 = 0, e1 = 0;
    int last = rs + nrows - 1;
#pragma unroll
    for (int e = 1; e < 8; ++e) {
        int v = eoff[e];
        if (v <= rs) e0 = e;
        if (v <= last) e1 = e;
    }
    int ne = e1 - e0 + 1;
    int nchunks = 2 * ne + 2;

    int lane = t & 63, rg = t >> 6;
    int cols = lane * 4;
    int srow = lane >> 3;                       // 0..7 within wave
    int sk = (lane & 7) * 8;                    // 0..56
    int gpos = rs + rg * 8 + srow;              // global perm position of my staged row
    int myrow = rows[rg * 8 + srow];
    float* stc = &a_tile[0][rg * 544 + srow * 68 + sk];
    float* stn = &a_tile[1][rg * 544 + srow * 68 + sk];
    const float* atc = &a_tile[0][rg * 544];
    const float* atn = &a_tile[1][rg * 544];

    float acc[8][4];
#pragma unroll
    for (int r = 0; r < 8; ++r) { acc[r][0] = 0.f; acc[r][1] = 0.f; acc[r][2] = 0.f; acc[r][3] = 0.f; }

    auto params = [&](int c, const float*& ap, const float*& Bp, float& m) {
        int half = c & 1;
        if (c < 2 * ne) {
            int e = e0 + (c >> 1);
            ap = agg + (size_t)myrow * DIN + sk + half * 64;
            Bp = B1 + (size_t)e * DIN * NCOL + (size_t)half * 64 * NCOL + cols;
            m = (gpos >= eoff[e] && gpos < eoff[e + 1]) ? 1.f : 0.f;
        } else {
            ap = a2 + (size_t)myrow * DIN + sk + half * 64;
            Bp = B2 + (size_t)half * 64 * NCOL + cols;
            m = 1.f;
        }
    };

    const float* ap; const float* Bp; float m;
    params(0, ap, Bp, m);
    float4 p0 = *(const float4*)ap, p1 = *(const float4*)(ap + 4);
#pragma unroll 1
    for (int c = 0; c < nchunks; ++c) {
        float4 s0 = p0, s1 = p1;
        s0.x *= m; s0.y *= m; s0.z *= m; s0.w *= m;
        s1.x *= m; s1.y *= m; s1.z *= m; s1.w *= m;
        *(float4*)stc = s0; *(float4*)(stc + 4) = s1;
        const float* Bcur = Bp;
        if (c + 1 < nchunks) {                  // prefetch next chunk's A (hidden under compute)
            params(c + 1, ap, Bp, m);
            p0 = *(const float4*)ap; p1 = *(const float4*)(ap + 4);
        }
        compute_chunk<NCOL>(Bcur, atc, acc);
        float* ts = stc; stc = stn; stn = ts;
        const float* ta = atc; atc = atn; atn = ta;
    }

#pragma unroll
    for (int r = 0; r < 8; ++r) {
        int rr = rg * 8 + r;
        if (rr < nrows) {
            int gp = rs + rr;
            int er = e0;
            for (int e = e0 + 1; e <= e1; ++e) if (eoff[e] <= gp) er = e;
            float4 bb = *(const float4*)(bias + er * NCOL + cols);
            int gr = rows[rr];
            float v0 = acc[r][0] + bb.x, v1 = acc[r][1] + bb.y;
            float v2 = acc[r][2] + bb.z, v3 = acc[r][3] + bb.w;
            if (RELU) { v0 = fmaxf(v0, 0.f); v1 = fmaxf(v1, 0.f); v2 = fmaxf(v2, 0.f); v3 = fmaxf(v3, 0.f); }
            *(float4*)(outp + (size_t)gr * NCOL + cols) = make_float4(v0, v1, v2, v3);
        }
    }
}

// ---------------- MFMA GEMM (layers 2/3). MODE 0: fp32 A -> f2bf in LDS.
// MODE 2: A already bf16, direct stage. MODE 9: half skipped entirely.
template<int DIN, int MODE, int CT>
DEV void gemm_half(const void* __restrict__ Asrc, const unsigned short* __restrict__ BT,
                   short (*Ah)[40], short (*Bs)[40],
                   const int* rows, f32x4 (&acc)[4][CT], int t, int lane, int w) {
    if (MODE == 9) return;
    int q = lane >> 4, m16 = lane & 15;
    int r = t >> 2, part = t & 3;
    for (int kc = 0; kc < DIN; kc += 32) {
        __syncthreads();
        if (MODE == 2) {
            *(uint4*)&Ah[r][part * 8] =
                *(const uint4*)((const unsigned short*)Asrc + (size_t)rows[r] * DIN + kc + part * 8);
        } else {
            const float* pf = (const float*)Asrc + (size_t)rows[r] * DIN + kc + part * 8;
            float4 p0 = *(const float4*)pf, p1 = *(const float4*)(pf + 4);
            float va[8] = { p0.x, p0.y, p0.z, p0.w, p1.x, p1.y, p1.z, p1.w };
            short8 h;
#pragma unroll
            for (int j = 0; j < 8; ++j) h[j] = (short)f2bf(va[j]);
            *(short8*)&Ah[r][part * 8] = h;
        }
#pragma unroll
        for (int j = 0; j < CT; ++j) {
            int c = t + 256 * j;
            int nn = c >> 2, pp = c & 3;
            *(uint4*)&Bs[nn][pp * 8] = *(const uint4*)(BT + (size_t)nn * DIN + kc + pp * 8);
        }
        __syncthreads();
        short8 af[4], bfr[CT];
#pragma unroll
        for (int rt = 0; rt < 4; ++rt) af[rt] = *(short8*)&Ah[rt * 16 + m16][q * 8];
#pragma unroll
        for (int ct = 0; ct < CT; ++ct) bfr[ct] = *(short8*)&Bs[w * CT * 16 + ct * 16 + m16][q * 8];
#pragma unroll
        for (int rt = 0; rt < 4; ++rt)
#pragma unroll
            for (int ct = 0; ct < CT; ++ct)
                acc[rt][ct] = __builtin_amdgcn_mfma_f32_16x16x32_bf16(af[rt], bfr[ct], acc[rt][ct], 0, 0, 0);
    }
}

// OUTMODE: 0 = fp32 store, 1 = bf16 store, 2 = split (cols<128 -> bf16 outp stride 128,
// cols>=128 -> fp32 outp2 stride 128; bias carries [0|bl3])
template<int DIN, int M0, int M1, int CT, bool EXPERT, bool RELU, int OUTMODE>
__global__ __launch_bounds__(256) void k_gemm(
    const void* __restrict__ A0, const void* __restrict__ A1,
    const unsigned short* __restrict__ B0T, const unsigned short* __restrict__ B1T,
    const float* __restrict__ bias,
    const int* __restrict__ perm, const int* __restrict__ eoff,
    void* __restrict__ outp, void* __restrict__ outp2, int n) {
    constexpr int NCOL = CT * 64;
    __shared__ short Ah[64][40];
    __shared__ short Bs[NCOL][40];
    __shared__ int rows[64];
    int t = threadIdx.x;
    int lane = t & 63, w = t >> 6;
    int e = 0, base = 0, cnt = n;
    if (EXPERT) { e = blockIdx.y; base = eoff[e]; cnt = eoff[e + 1] - base; }
    int rs = blockIdx.x * 64;
    if (rs >= cnt) return;
    int nrows = min(64, cnt - rs);
    if (t < 64) {
        int j = rs + min(t, nrows - 1);
        rows[t] = EXPERT ? perm[base + j] : j;
    }
    __syncthreads();
    f32x4 acc[4][CT];
#pragma unroll
    for (int rt = 0; rt < 4; ++rt)
#pragma unroll
        for (int ct = 0; ct < CT; ++ct) acc[rt][ct] = (f32x4)(0.f);

    gemm_half<DIN, M0, CT>(A0, B0T + (EXPERT ? (size_t)e * DIN * NCOL : 0), Ah, Bs, rows, acc, t, lane, w);
    gemm_half<DIN, M1, CT>(A1, B1T, Ah, Bs, rows, acc, t, lane, w);

    int q = lane >> 4, m16 = lane & 15;
#pragma unroll
    for (int ct = 0; ct < CT; ++ct) {
        int col = w * CT * 16 + ct * 16 + m16;
        float bv = bias[(EXPERT ? e * NCOL : 0) + col];
#pragma unroll
        for (int rt = 0; rt < 4; ++rt)
#pragma unroll
            for (int i = 0; i < 4; ++i) {
                int rr = rt * 16 + q * 4 + i;
                if (rr < nrows) {
                    int gr = rows[rr];
                    float v = acc[rt][ct][i] + bv;
                    if (RELU) v = fmaxf(v, 0.f);
                    if (OUTMODE == 1) ((unsigned short*)outp)[(size_t)gr * NCOL + col] = f2bf(v);
                    else if (OUTMODE == 0) ((float*)outp)[(size_t)gr * NCOL + col] = v;
                    else {
                        if (col < 128) ((unsigned short*)outp)[(size_t)gr * 128 + col] = f2bf(v);
                        else           ((float*)outp2)[(size_t)gr * 128 + (col - 128)] = v;
                    }
                }
            }
    }
}

__global__ void k_final(const float* __restrict__ gsum, float* __restrict__ outf) {
    if (threadIdx.x == 0 && blockIdx.x == 0) {
        float g = (gsum[0] + gsum[1]) * (0.5f / 50000.0f);
        outf[(size_t)50000 * 128] = g;   // output buffer is fp32
    }
}

extern "C" void kernel_launch(void* const* d_in, const int* in_sizes, int n_in,
                              void* d_out, int out_size, void* d_ws, size_t ws_size,
                              hipStream_t stream) {
    constexpr int N = 50000, E = 800000;
    const float* x   = (const float*)d_in[0];
    const int* ei    = (const int*)d_in[1];
    const float* wg1 = (const float*)d_in[2];
    const float* bg1 = (const float*)d_in[3];
    const float* we1 = (const float*)d_in[4];
    const float* be1 = (const float*)d_in[5];
    const float* wr1 = (const float*)d_in[6];
    const float* wg2 = (const float*)d_in[7];
    const float* bg2 = (const float*)d_in[8];
    const float* we2 = (const float*)d_in[9];
    const float* be2 = (const float*)d_in[10];
    const float* wr2 = (const float*)d_in[11];
    const float* wl3 = (const float*)d_in[12];
    const float* bl3 = (const float*)d_in[13];
    const float* wr3 = (const float*)d_in[14];

    // ---- workspace layout ----
    int* ip = (int*)d_ws;
    int* deg = ip;            ip += N;
    int* cursor = ip;         ip += N;
    int* ecnt = ip;           ip += 16;
    int* ecur = ip;           ip += 16;
    float* gsum = (float*)ip; ip += 2;
    int* flags = ip;          ip += 2;
    float* bias3 = (float*)ip; ip += 256;
    int* row_ptr = ip;        ip += N + 1;
    int* csr = ip;            ip += E;
    int* idxb = ip;           ip += N;
    int* permb = ip;          ip += N;
    int* eoff = ip;           ip += 18;
    int* part = ip;           ip += 256;
    int* src32 = ip;          ip += E;
    int* dst32 = ip;          ip += E;
    size_t off = (size_t)((char*)ip - (char*)d_ws);
    off = (off + 255) & ~(size_t)255;
    float* fp = (float*)((char*)d_ws + off);
    float* agg = fp; fp += (size_t)N * 256;            // fp32 agg (layers 1-2)
    float* h1  = fp; fp += (size_t)N * 256;            // fp32 h1 (gate-2 critical)
    unsigned short* wp = (unsigned short*)fp;
    unsigned short* h2b  = wp; wp += (size_t)N * 256;  // bf16 h2 (gate-free)
    unsigned short* we2T = wp; wp += 8 * 256 * 256;    // bf16 B^T [n][k]
    unsigned short* wr2T = wp; wp += 256 * 256;
    unsigned short* wl3T = wp; wp += 256 * 128;        // + wr3T adjacent = [256][256] B^T
    unsigned short* wr3T = wp; wp += 256 * 128;
    // layer-3 swap buffers alias dead regions (agg/h1 unused after layer-2 gemm)
    unsigned short* Pb = (unsigned short*)h1;          // bf16 [N][128] = h2b @ wl3
    float* Rf = agg;                                   // fp32 [N][128] = h2b @ wr3 + bl3

    hipMemsetAsync(d_ws, 0, (size_t)(2 * N + 36) * 4, stream);

    k_detect<<<1, 64, 0, stream>>>(ei, flags);
    k_cvt_idx<<<(E + 255) / 256, 256, 0, stream>>>(ei, src32, dst32, deg, E, flags);

    // fused transpose+narrow to bf16 B^T [n][k] (layers 2/3)
    k_transpose_nb<<<dim3(8, 8, 8), 256, 0, stream>>>(we2, we2T, 256, 256);
    k_transpose_nb<<<dim3(8, 8, 1), 256, 0, stream>>>(wr2, wr2T, 256, 256);
    k_transpose_nb<<<dim3(4, 8, 1), 256, 0, stream>>>(wl3, wl3T, 256, 128);
    k_transpose_nb<<<dim3(4, 8, 1), 256, 0, stream>>>(wr3, wr3T, 256, 128);
    k_bias3<<<1, 256, 0, stream>>>(bl3, bias3);

    // CSR (degree fused into k_cvt_idx)
    constexpr int NB = (N + 255) / 256;
    constexpr int WB = (N + 3) / 4;
    k_scan1<<<NB, 256, 0, stream>>>(deg, row_ptr, part, N);
    k_scan2<<<1, 256, 0, stream>>>(part, NB);
    k_scan3<<<NB, 256, 0, stream>>>(row_ptr, part, N, E);
    k_fill<<<(E + 255) / 256, 256, 0, stream>>>(src32, dst32, row_ptr, cursor, csr, E);

    constexpr int GB = (N + 63) / 64;      // 64-row tiles (MFMA layers 2/3)
    constexpr int GB32 = (N + 31) / 32;    // 32-row tiles (VALU layer 1, compact grid)
    // ---- layer 1: 128 -> 256, MoE + root(x), relu — VALU fp32 (h1 bit-identical) ----
    k_aggr<128><<<WB, 256, 0, stream>>>(x, row_ptr, csr, agg, N);
    k_gate<128><<<NB, 256, 0, stream>>>(agg, wg1, bg1, idxb, ecnt, gsum, N);
    k_offsets<<<1, 1, 0, stream>>>(ecnt, eoff);
    k_perm<<<NB, 256, 0, stream>>>(idxb, eoff, ecur, permb, N);
    k_gemm_f32<128, 256, true><<<dim3(GB32), 256, 0, stream>>>(
        agg, x, we1, wr1, be1, permb, eoff, h1, N);

    // ---- layer 2: 256 -> 256, MoE + root(h1), relu — MFMA dim3(GB,8); bf16 h2b out ----
    k_aggr<256><<<WB, 256, 0, stream>>>(h1, row_ptr, csr, agg, N);
    k_gate<256><<<NB, 256, 0, stream>>>(agg, wg2, bg2, idxb, ecnt + 8, gsum + 1, N);
    k_offsets<<<1, 1, 0, stream>>>(ecnt + 8, eoff + 9);
    k_perm<<<NB, 256, 0, stream>>>(idxb, eoff + 9, ecur + 8, permb, N);
    k_gemm<256, 0, 0, 4, true, true, 1><<<dim3(GB, 8), 256, 0, stream>>>(
        agg, h1, we2T, wr2T, be2, permb, eoff + 9, h2b, nullptr, N);

    // ---- layer 3 (linearity swap): [P|R] = h2b @ [wl3|wr3]; out = mean_aggr(P) + R ----
    k_gemm<256, 2, 9, 4, false, false, 2><<<dim3(GB, 1), 256, 0, stream>>>(
        h2b, nullptr, wl3T, nullptr, bias3, nullptr, nullptr, Pb, Rf, N);
    k_aggr_badd<<<WB, 256, 0, stream>>>(Pb, row_ptr, csr, Rf, (float*)d_out, N);

    k_final<<<1, 1, 0, stream>>>(gsum, (float*)d_out);
}

// Round 9
// 644.245 us; speedup vs baseline: 1.0440x; 1.0164x over previous
//
#include <hip/hip_runtime.h>
#include <hip/hip_bf16.h>
#include <stdint.h>

#define DEV static __device__ __forceinline__

typedef __attribute__((ext_vector_type(8))) short short8;   // 8 bf16 (4 VGPRs)
typedef __attribute__((ext_vector_type(4))) float f32x4;    // MFMA accumulator

DEV float bf2f(unsigned short u) { return __uint_as_float(((unsigned)u) << 16); }
DEV float bflo(unsigned u) { return __uint_as_float(u << 16); }
DEV float bfhi(unsigned u) { return __uint_as_float(u & 0xffff0000u); }
DEV unsigned short f2bf(float f) {
    unsigned u = __float_as_uint(f);
    u += 0x7fff + ((u >> 16) & 1);   // RNE
    return (unsigned short)(u >> 16);
}

// ---------------- edge_index width detection (int64 vs int32) ----------------
__global__ void k_detect(const int* __restrict__ ei, int* __restrict__ flags) {
    if (threadIdx.x == 0 && blockIdx.x == 0) {
        int zeros = 0;
        for (int i = 0; i < 128; ++i) if (ei[2 * i + 1] == 0) ++zeros;
        flags[1] = (zeros >= 64) ? 1 : 0;
    }
}

// fused: index narrow + degree count (saves a separate 800k-element pass)
__global__ void k_cvt_idx(const int* __restrict__ ei, int* __restrict__ src32,
                          int* __restrict__ dst32, int* __restrict__ deg,
                          int E, const int* __restrict__ flags) {
    int i = blockIdx.x * 256 + threadIdx.x;
    if (i >= E) return;
    int s, d;
    if (flags[1]) { s = ei[2 * i]; d = ei[2 * E + 2 * i]; }
    else          { s = ei[i];     d = ei[E + i]; }
    src32[i] = s; dst32[i] = d;
    atomicAdd(&deg[d], 1);
}

// ---------------- fused transpose+narrow: fp32 in[r][c] -> bf16 out[c][r] ----------------
__global__ void k_transpose_nb(const float* __restrict__ in, unsigned short* __restrict__ out,
                               int R, int C) {
    __shared__ unsigned short tile[32][33];
    int tx = threadIdx.x & 31, ty = threadIdx.x >> 5;   // 256 threads = 32x8
    size_t mat = (size_t)blockIdx.z * R * C;
    int r0 = blockIdx.y * 32, c0 = blockIdx.x * 32;
#pragma unroll
    for (int j = 0; j < 32; j += 8)
        tile[ty + j][tx] = f2bf(in[mat + (size_t)(r0 + ty + j) * C + c0 + tx]);
    __syncthreads();
#pragma unroll
    for (int j = 0; j < 32; j += 8)
        out[mat + (size_t)(c0 + ty + j) * R + r0 + tx] = tile[tx][ty + j];
}

// bias for the fused layer-3 GEMM: cols 0..127 (P half) get 0, cols 128..255 get bl3
__global__ void k_bias3(const float* __restrict__ bl3, float* __restrict__ bias3) {
    int t = threadIdx.x;
    bias3[t] = (t < 128) ? 0.f : bl3[t - 128];
}

// ---------------- CSR build: degree (fused above) -> 3-phase shfl scan -> fill ----------------
__global__ void k_scan1(const int* __restrict__ deg, int* __restrict__ row_ptr,
                        int* __restrict__ part, int n) {
    __shared__ int wsum[4];
    int t = threadIdx.x, lane = t & 63, wv = t >> 6;
    int i = blockIdx.x * 256 + t;
    int v0 = (i < n) ? deg[i] : 0;
    int v = v0;
#pragma unroll
    for (int d = 1; d < 64; d <<= 1) { int u = __shfl_up(v, d); if (lane >= d) v += u; }
    if (lane == 63) wsum[wv] = v;
    __syncthreads();
    int add = 0;
    for (int w2 = 0; w2 < wv; ++w2) add += wsum[w2];
    v += add;
    if (i < n) row_ptr[i] = v - v0;            // block-local exclusive
    if (t == 255) part[blockIdx.x] = v;        // block total
}

__global__ void k_scan2(int* __restrict__ part, int P) {
    __shared__ int wsum[4];
    int t = threadIdx.x, lane = t & 63, wv = t >> 6;
    int v0 = (t < P) ? part[t] : 0;
    int v = v0;
#pragma unroll
    for (int d = 1; d < 64; d <<= 1) { int u = __shfl_up(v, d); if (lane >= d) v += u; }
    if (lane == 63) wsum[wv] = v;
    __syncthreads();
    int add = 0;
    for (int w2 = 0; w2 < wv; ++w2) add += wsum[w2];
    v += add;
    if (t < P) part[t] = v - v0;               // exclusive over partials
}

__global__ void k_scan3(int* __restrict__ row_ptr, const int* __restrict__ part, int n, int E) {
    int i = blockIdx.x * 256 + threadIdx.x;
    if (i < n) row_ptr[i] += part[blockIdx.x];
    if (i == 0) row_ptr[n] = E;
}

__global__ void k_fill(const int* __restrict__ src, const int* __restrict__ dst,
                       const int* __restrict__ row_ptr, int* __restrict__ cursor,
                       int* __restrict__ csr, int E) {
    int i = blockIdx.x * 256 + threadIdx.x;
    if (i < E) {
        int d = dst[i];
        int p = atomicAdd(&cursor[d], 1);
        csr[row_ptr[d] + p] = src[i];
    }
}
// NOTE (round-16): per-list src sort tried — FETCH unchanged, +94 us. Reverted.
// NOTE (round-17): compact-grid MFMA MoE GEMM tried — +18 us. Chaff blocks in
// dim3(GB,8) exit before any barrier; dispatch drain is ~free. Reverted.
// NOTE (round-18): 8-row unroll on the gather: +3% only. The ~3.9 TB/s gather
// plateau is bandwidth-proportional -> round-19 halves BYTES (bf16 h1) instead.

// ---------------- mean aggregation: one wave/node, fp64 accumulate, 8-row unroll ----------------
template<int D>
__global__ __launch_bounds__(256, 2) void k_aggr(
    const float* __restrict__ xin, const int* __restrict__ row_ptr,
    const int* __restrict__ csr, float* __restrict__ agg, int n) {
    int wid = (blockIdx.x * blockDim.x + threadIdx.x) >> 6;
    int lane = threadIdx.x & 63;
    if (wid >= n) return;
    constexpr int V = D / 64;
    double ac[8][V];
#pragma unroll
    for (int r = 0; r < 8; ++r)
#pragma unroll
        for (int i = 0; i < V; ++i) ac[r][i] = 0.0;
    int s0 = row_ptr[wid], s1 = row_ptr[wid + 1];
    int j = s0;
    for (; j + 8 <= s1; j += 8) {
        const float* p[8];
#pragma unroll
        for (int r = 0; r < 8; ++r) p[r] = xin + (size_t)csr[j + r] * D + lane * V;
        if (V == 2) {
            float2 f[8];
#pragma unroll
            for (int r = 0; r < 8; ++r) f[r] = *(const float2*)p[r];
#pragma unroll
            for (int r = 0; r < 8; ++r) { ac[r][0] += (double)f[r].x; ac[r][1] += (double)f[r].y; }
        } else {
            float4 f[8];
#pragma unroll
            for (int r = 0; r < 8; ++r) f[r] = *(const float4*)p[r];
#pragma unroll
            for (int r = 0; r < 8; ++r) {
                ac[r][0] += (double)f[r].x; ac[r][1] += (double)f[r].y;
                ac[r][2] += (double)f[r].z; ac[r][3] += (double)f[r].w;
            }
        }
    }
    for (; j + 4 <= s1; j += 4) {
        const float* p[4];
#pragma unroll
        for (int r = 0; r < 4; ++r) p[r] = xin + (size_t)csr[j + r] * D + lane * V;
        if (V == 2) {
            float2 f[4];
#pragma unroll
            for (int r = 0; r < 4; ++r) f[r] = *(const float2*)p[r];
#pragma unroll
            for (int r = 0; r < 4; ++r) { ac[r][0] += (double)f[r].x; ac[r][1] += (double)f[r].y; }
        } else {
            float4 f[4];
#pragma unroll
            for (int r = 0; r < 4; ++r) f[r] = *(const float4*)p[r];
#pragma unroll
            for (int r = 0; r < 4; ++r) {
                ac[r][0] += (double)f[r].x; ac[r][1] += (double)f[r].y;
                ac[r][2] += (double)f[r].z; ac[r][3] += (double)f[r].w;
            }
        }
    }
    for (; j < s1; ++j) {
        const float* p = xin + (size_t)csr[j] * D + lane * V;
        if (V == 2) {
            float2 f = *(const float2*)p;
            ac[0][0] += (double)f.x; ac[0][1] += (double)f.y;
        } else {
            float4 f = *(const float4*)p;
            ac[0][0] += (double)f.x; ac[0][1] += (double)f.y;
            ac[0][2] += (double)f.z; ac[0][3] += (double)f.w;
        }
    }
    double inv = 1.0 / (double)max(s1 - s0, 1);
#pragma unroll
    for (int i = 0; i < V; ++i) {
        double s = ((ac[0][i] + ac[1][i]) + (ac[2][i] + ac[3][i]))
                 + ((ac[4][i] + ac[5][i]) + (ac[6][i] + ac[7][i]));
        agg[(size_t)wid * D + lane * V + i] = (float)(s * inv);
    }
}

// Round-19: layer-2 gather reads bf16 h1b (512 B/row, HALF the fp32 bytes) and
// writes bf16 agg for the MODE-2 GEMM stage. Gate-2 no longer depends on this
// (computed from G2 — see k_gemm_f32 epilogue + k_gate_g). Numeric delta vs fp32
// path: h1 quantized to bf16 BEFORE the mean (~0.1% of h1 scale) — same class as
// the bf16 MFMA GEMM it feeds. Gate-free.
__global__ __launch_bounds__(256, 2) void k_aggr_h1b(
    const unsigned short* __restrict__ xin, const int* __restrict__ row_ptr,
    const int* __restrict__ csr, unsigned short* __restrict__ aggb, int n) {
    int wid = (blockIdx.x * blockDim.x + threadIdx.x) >> 6;
    int lane = threadIdx.x & 63;
    if (wid >= n) return;
    double ac[8][4];
#pragma unroll
    for (int r = 0; r < 8; ++r)
#pragma unroll
        for (int i = 0; i < 4; ++i) ac[r][i] = 0.0;
    int s0 = row_ptr[wid], s1 = row_ptr[wid + 1];
    int j = s0;
    for (; j + 8 <= s1; j += 8) {
        uint2 u[8];
#pragma unroll
        for (int r = 0; r < 8; ++r) u[r] = *(const uint2*)(xin + (size_t)csr[j + r] * 256 + lane * 4);
#pragma unroll
        for (int r = 0; r < 8; ++r) {
            ac[r][0] += (double)bflo(u[r].x); ac[r][1] += (double)bfhi(u[r].x);
            ac[r][2] += (double)bflo(u[r].y); ac[r][3] += (double)bfhi(u[r].y);
        }
    }
    for (; j + 4 <= s1; j += 4) {
        uint2 u[4];
#pragma unroll
        for (int r = 0; r < 4; ++r) u[r] = *(const uint2*)(xin + (size_t)csr[j + r] * 256 + lane * 4);
#pragma unroll
        for (int r = 0; r < 4; ++r) {
            ac[r][0] += (double)bflo(u[r].x); ac[r][1] += (double)bfhi(u[r].x);
            ac[r][2] += (double)bflo(u[r].y); ac[r][3] += (double)bfhi(u[r].y);
        }
    }
    for (; j < s1; ++j) {
        uint2 u = *(const uint2*)(xin + (size_t)csr[j] * 256 + lane * 4);
        ac[0][0] += (double)bflo(u.x); ac[0][1] += (double)bfhi(u.x);
        ac[0][2] += (double)bflo(u.y); ac[0][3] += (double)bfhi(u.y);
    }
    double inv = 1.0 / (double)max(s1 - s0, 1);
    float m[4];
#pragma unroll
    for (int i = 0; i < 4; ++i) {
        double s = ((ac[0][i] + ac[1][i]) + (ac[2][i] + ac[3][i]))
                 + ((ac[4][i] + ac[5][i]) + (ac[6][i] + ac[7][i]));
        m[i] = (float)(s * inv);
    }
    unsigned b01 = (unsigned)f2bf(m[0]) | ((unsigned)f2bf(m[1]) << 16);
    unsigned b23 = (unsigned)f2bf(m[2]) | ((unsigned)f2bf(m[3]) << 16);
    *(uint2*)(aggb + (size_t)wid * 256 + lane * 4) = make_uint2(b01, b23);
}

// Layer-3 fused gather (8-row unroll): P is bf16 [n][128]; out = mean(P[nbrs]) + R.
__global__ __launch_bounds__(256, 2) void k_aggr_badd(
    const unsigned short* __restrict__ Pb, const int* __restrict__ row_ptr,
    const int* __restrict__ csr, const float* __restrict__ Rf,
    float* __restrict__ outp, int n) {
    int wid = (blockIdx.x * blockDim.x + threadIdx.x) >> 6;
    int lane = threadIdx.x & 63;
    if (wid >= n) return;
    double ac[8][2];
#pragma unroll
    for (int r = 0; r < 8; ++r) { ac[r][0] = 0.0; ac[r][1] = 0.0; }
    int s0 = row_ptr[wid], s1 = row_ptr[wid + 1];
    int j = s0;
    for (; j + 8 <= s1; j += 8) {
        unsigned u[8];
#pragma unroll
        for (int r = 0; r < 8; ++r) u[r] = *(const unsigned*)(Pb + (size_t)csr[j + r] * 128 + lane * 2);
#pragma unroll
        for (int r = 0; r < 8; ++r) { ac[r][0] += (double)bflo(u[r]); ac[r][1] += (double)bfhi(u[r]); }
    }
    for (; j + 4 <= s1; j += 4) {
        unsigned u[4];
#pragma unroll
        for (int r = 0; r < 4; ++r) u[r] = *(const unsigned*)(Pb + (size_t)csr[j + r] * 128 + lane * 2);
#pragma unroll
        for (int r = 0; r < 4; ++r) { ac[r][0] += (double)bflo(u[r]); ac[r][1] += (double)bfhi(u[r]); }
    }
    for (; j < s1; ++j) {
        unsigned u = *(const unsigned*)(Pb + (size_t)csr[j] * 128 + lane * 2);
        ac[0][0] += (double)bflo(u); ac[0][1] += (double)bfhi(u);
    }
    double inv = 1.0 / (double)max(s1 - s0, 1);
    float2 r2 = *(const float2*)(Rf + (size_t)wid * 128 + lane * 2);
    float2 o;
    o.x = (float)((((ac[0][0] + ac[1][0]) + (ac[2][0] + ac[3][0]))
                 + ((ac[4][0] + ac[5][0]) + (ac[6][0] + ac[7][0]))) * inv) + r2.x;
    o.y = (float)((((ac[0][1] + ac[1][1]) + (ac[2][1] + ac[3][1]))
                 + ((ac[4][1] + ac[5][1]) + (ac[6][1] + ac[7][1]))) * inv) + r2.y;
    *(float2*)(outp + (size_t)wid * 128 + lane * 2) = o;
}

// ---------------- gate-1 (round-5 verbatim; fp32 weights read directly) ----------------
template<int D>
__global__ void k_gate(const float* __restrict__ agg, const float* __restrict__ wg,
                       const float* __restrict__ bg, int* __restrict__ idx,
                       int* __restrict__ ecnt, float* __restrict__ gsum, int n) {
    __shared__ float swg[D * 8];
    __shared__ int hcnt[8];
    __shared__ float red[256];
    int t = threadIdx.x;
    if (t < 8) hcnt[t] = 0;
    for (int i = t; i < D * 8; i += 256) swg[i] = wg[i];
    __syncthreads();
    int nid = blockIdx.x * 256 + t;
    float stdv = 0.f;
    if (nid < n) {
        double lg[8];
#pragma unroll
        for (int e = 0; e < 8; ++e) lg[e] = (double)bg[e];
        const float* ap = agg + (size_t)nid * D;
        for (int k = 0; k < D; k += 4) {
            float4 a = *(const float4*)(ap + k);
#pragma unroll
            for (int e = 0; e < 8; ++e) {
                lg[e] += (double)a.x * swg[(k + 0) * 8 + e] + (double)a.y * swg[(k + 1) * 8 + e]
                       + (double)a.z * swg[(k + 2) * 8 + e] + (double)a.w * swg[(k + 3) * 8 + e];
            }
        }
        double m = lg[0];
        int am = 0;
#pragma unroll
        for (int e = 1; e < 8; ++e) if (lg[e] > m) { m = lg[e]; am = e; }
        double s = 0.0, p[8];
#pragma unroll
        for (int e = 0; e < 8; ++e) { p[e] = exp(lg[e] - m); s += p[e]; }
        double invs = 1.0 / s, sq = 0.0;
#pragma unroll
        for (int e = 0; e < 8; ++e) { double q = p[e] * invs; sq += q * q; }
        stdv = (float)sqrt(fmax(sq - 0.125, 0.0) / 7.0);
        idx[nid] = am;
        atomicAdd(&hcnt[am], 1);
    }
    red[t] = stdv;
    __syncthreads();
    for (int off = 128; off > 0; off >>= 1) {
        if (t < off) red[t] += red[t + off];
        __syncthreads();
    }
    if (t == 0) atomicAdd(gsum, red[0]);
    if (t < 8 && hcnt[t] > 0) atomicAdd(&ecnt[t], hcnt[t]);
}

// ---------------- gate-2 from G2 (linearity swap, round-19) ----------------
// logits2 = mean(relu(h1)) @ wg2 + bg2 == mean(relu(h1) @ wg2) + bg2.
// G2 is fp64 (3.2 MB, L2-resident per XCD). vs the old fp32-agg path this drops
// one fp32 rounding (~1e-7 logit delta) — below the ~1e-6 argmax cliff.
__global__ void k_gate_g(const double* __restrict__ G2, const int* __restrict__ row_ptr,
                         const int* __restrict__ csr, const float* __restrict__ bg,
                         int* __restrict__ idx, int* __restrict__ ecnt,
                         float* __restrict__ gsum, int n) {
    __shared__ int hcnt[8];
    __shared__ float red[256];
    int t = threadIdx.x;
    if (t < 8) hcnt[t] = 0;
    __syncthreads();
    int nid = blockIdx.x * 256 + t;
    float stdv = 0.f;
    if (nid < n) {
        double lg[8];
#pragma unroll
        for (int e = 0; e < 8; ++e) lg[e] = 0.0;
        int s0 = row_ptr[nid], s1 = row_ptr[nid + 1];
        for (int j = s0; j < s1; ++j) {
            const double* g = G2 + (size_t)csr[j] * 8;
            double2 g0 = *(const double2*)g,       g1 = *(const double2*)(g + 2);
            double2 g2 = *(const double2*)(g + 4), g3 = *(const double2*)(g + 6);
            lg[0] += g0.x; lg[1] += g0.y; lg[2] += g1.x; lg[3] += g1.y;
            lg[4] += g2.x; lg[5] += g2.y; lg[6] += g3.x; lg[7] += g3.y;
        }
        double inv = 1.0 / (double)max(s1 - s0, 1);
#pragma unroll
        for (int e = 0; e < 8; ++e) lg[e] = lg[e] * inv + (double)bg[e];
        double m = lg[0];
        int am = 0;
#pragma unroll
        for (int e = 1; e < 8; ++e) if (lg[e] > m) { m = lg[e]; am = e; }
        double s = 0.0, p[8];
#pragma unroll
        for (int e = 0; e < 8; ++e) { p[e] = exp(lg[e] - m); s += p[e]; }
        double invs = 1.0 / s, sq = 0.0;
#pragma unroll
        for (int e = 0; e < 8; ++e) { double q = p[e] * invs; sq += q * q; }
        stdv = (float)sqrt(fmax(sq - 0.125, 0.0) / 7.0);
        idx[nid] = am;
        atomicAdd(&hcnt[am], 1);
    }
    red[t] = stdv;
    __syncthreads();
    for (int off = 128; off > 0; off >>= 1) {
        if (t < off) red[t] += red[t + off];
        __syncthreads();
    }
    if (t == 0) atomicAdd(gsum, red[0]);
    if (t < 8 && hcnt[t] > 0) atomicAdd(&ecnt[t], hcnt[t]);
}

__global__ void k_offsets(const int* __restrict__ ecnt, int* __restrict__ eoff) {
    if (threadIdx.x == 0 && blockIdx.x == 0) {
        int s = 0;
        for (int e = 0; e < 8; ++e) { eoff[e] = s; s += ecnt[e]; }
        eoff[8] = s;
    }
}

__global__ void k_perm(const int* __restrict__ idx, const int* __restrict__ eoff,
                       int* __restrict__ ecur, int* __restrict__ perm, int n) {
    __shared__ int lcnt[8], lbase[8];
    int t = threadIdx.x;
    if (t < 8) lcnt[t] = 0;
    __syncthreads();
    int nid = blockIdx.x * 256 + t;
    int e = 0, r = 0;
    bool valid = (nid < n);
    if (valid) { e = idx[nid]; r = atomicAdd(&lcnt[e], 1); }
    __syncthreads();
    if (t < 8) lbase[t] = lcnt[t] ? atomicAdd(&ecur[t], lcnt[t]) : 0;
    __syncthreads();
    if (valid) perm[eoff[e] + lbase[e] + r] = nid;
}

// ---------------- VALU fp32 GEMM, layer 1 (compact grid; h1 VALUES bit-identical) ----
// Round-19 epilogue additions: (a) h1 stored bf16 (h1b) — the layer-2 root A was
// f2bf(h1) at stage time anyway, so those bits are IDENTICAL; write traffic halves.
// (b) G2[row][e] = relu(h1_row) @ wg2 in fp64 (each wave holds a full 256-col row
// across its 64 lanes — 32 fp64 FMA + 8 shfl_xor reduces per row). Gate-2 reads G2.
template<int NCOL, bool LOAD>
DEV void g_step(int g, const float* __restrict__ Bp, const float* __restrict__ at,
                float4 (&cur)[4], float (&acc)[8][4]) {
    float bx[4][4];
#pragma unroll
    for (int kk = 0; kk < 4; ++kk) {
        bx[kk][0] = cur[kk].x; bx[kk][1] = cur[kk].y;
        bx[kk][2] = cur[kk].z; bx[kk][3] = cur[kk].w;
    }
#pragma unroll
    for (int r = 0; r < 8; ++r) {
        float4 a = *(const float4*)(at + r * 68 + g * 4);   // uniform addr -> LDS broadcast
#pragma unroll
        for (int c = 0; c < 4; ++c) {
            acc[r][c] = fmaf(a.x, bx[0][c], acc[r][c]);
            acc[r][c] = fmaf(a.y, bx[1][c], acc[r][c]);
            acc[r][c] = fmaf(a.z, bx[2][c], acc[r][c]);
            acc[r][c] = fmaf(a.w, bx[3][c], acc[r][c]);
        }
    }
    if (LOAD) {
#pragma unroll
        for (int kk = 0; kk < 4; ++kk)
            cur[kk] = *(const float4*)(Bp + (size_t)(g * 4 + 8 + kk) * NCOL);
    }
}

template<int NCOL>
DEV void compute_chunk(const float* __restrict__ Bp, const float* __restrict__ at,
                       float (&acc)[8][4]) {
    float4 bA[4], bB[4];
#pragma unroll
    for (int kk = 0; kk < 4; ++kk) bA[kk] = *(const float4*)(Bp + (size_t)kk * NCOL);
#pragma unroll
    for (int kk = 0; kk < 4; ++kk) bB[kk] = *(const float4*)(Bp + (size_t)(4 + kk) * NCOL);
#pragma unroll 1
    for (int g = 0; g < 14; g += 2) {          // rolled: keep body ~2.5 KB for I$
        g_step<NCOL, true>(g, Bp, at, bA, acc);
        g_step<NCOL, true>(g + 1, Bp, at, bB, acc);
    }
    g_step<NCOL, false>(14, Bp, at, bA, acc);
    g_step<NCOL, false>(15, Bp, at, bB, acc);
}

template<int DIN, int NCOL, bool RELU>
__global__ __launch_bounds__(256, 4) void k_gemm_f32(
    const float* __restrict__ agg, const float* __restrict__ a2,
    const float* __restrict__ B1, const float* __restrict__ B2,
    const float* __restrict__ bias, const float* __restrict__ wg2,
    const int* __restrict__ perm, const int* __restrict__ eoff,
    unsigned short* __restrict__ h1b, double* __restrict__ G2, int n) {
    static_assert(DIN == 128 && NCOL == 256, "layer-1 geometry");
    __shared__ float a_tile[2][4 * 8 * 68];
    __shared__ int rows[32];
    int t = threadIdx.x;
    int rs = blockIdx.x * 32;
    if (rs >= n) return;
    int nrows = min(32, n - rs);
    if (t < 32) rows[t] = perm[rs + min(t, nrows - 1)];
    __syncthreads();                            // the only barrier in this kernel

    int e0 = 0, e1 = 0;
    int last = rs + nrows - 1;
#pragma unroll
    for (int e = 1; e < 8; ++e) {
        int v = eoff[e];
        if (v <= rs) e0 = e;
        if (v <= last) e1 = e;
    }
    int ne = e1 - e0 + 1;
    int nchunks = 2 * ne + 2;

    int lane = t & 63, rg = t >> 6;
    int cols = lane * 4;
    int srow = lane >> 3;                       // 0..7 within wave
    int sk = (lane & 7) * 8;                    // 0..56
    int gpos = rs + rg * 8 + srow;              // global perm position of my staged row
    int myrow = rows[rg * 8 + srow];
    float* stc = &a_tile[0][rg * 544 + srow * 68 + sk];
    float* stn = &a_tile[1][rg * 544 + srow * 68 + sk];
    const float* atc = &a_tile[0][rg * 544];
    const float* atn = &a_tile[1][rg * 544];

    float acc[8][4];
#pragma unroll
    for (int r = 0; r < 8; ++r) { acc[r][0] = 0.f; acc[r][1] = 0.f; acc[r][2] = 0.f; acc[r][3] = 0.f; }

    auto params = [&](int c, const float*& ap, const float*& Bp, float& m) {
        int half = c & 1;
        if (c < 2 * ne) {
            int e = e0 + (c >> 1);
            ap = agg + (size_t)myrow * DIN + sk + half * 64;
            Bp = B1 + (size_t)e * DIN * NCOL + (size_t)half * 64 * NCOL + cols;
            m = (gpos >= eoff[e] && gpos < eoff[e + 1]) ? 1.f : 0.f;
        } else {
            ap = a2 + (size_t)myrow * DIN + sk + half * 64;
            Bp = B2 + (size_t)half * 64 * NCOL + cols;
            m = 1.f;
        }
    };

    const float* ap; const float* Bp; float m;
    params(0, ap, Bp, m);
    float4 p0 = *(const float4*)ap, p1 = *(const float4*)(ap + 4);
#pragma unroll 1
    for (int c = 0; c < nchunks; ++c) {
        float4 s0 = p0, s1 = p1;
        s0.x *= m; s0.y *= m; s0.z *= m; s0.w *= m;
        s1.x *= m; s1.y *= m; s1.z *= m; s1.w *= m;
        *(float4*)stc = s0; *(float4*)(stc + 4) = s1;
        const float* Bcur = Bp;
        if (c + 1 < nchunks) {                  // prefetch next chunk's A (hidden under compute)
            params(c + 1, ap, Bp, m);
            p0 = *(const float4*)ap; p1 = *(const float4*)(ap + 4);
        }
        compute_chunk<NCOL>(Bcur, atc, acc);
        float* ts = stc; stc = stn; stn = ts;
        const float* ta = atc; atc = atn; atn = ta;
    }

    // epilogue-only wg2 registers (loaded late -> no main-loop VGPR pressure)
    float wreg[4][8];
    {
        const float* wp2 = wg2 + (size_t)cols * 8;
#pragma unroll
        for (int c = 0; c < 4; ++c) {
            float4 wa = *(const float4*)(wp2 + c * 8);
            float4 wb = *(const float4*)(wp2 + c * 8 + 4);
            wreg[c][0] = wa.x; wreg[c][1] = wa.y; wreg[c][2] = wa.z; wreg[c][3] = wa.w;
            wreg[c][4] = wb.x; wreg[c][5] = wb.y; wreg[c][6] = wb.z; wreg[c][7] = wb.w;
        }
    }

#pragma unroll
    for (int r = 0; r < 8; ++r) {
        int rr = rg * 8 + r;                    // wave-uniform -> shfl-safe guard
        if (rr < nrows) {
            int gp = rs + rr;
            int er = e0;
            for (int e = e0 + 1; e <= e1; ++e) if (eoff[e] <= gp) er = e;
            float4 bb = *(const float4*)(bias + er * NCOL + cols);
            int gr = rows[rr];
            float v0 = acc[r][0] + bb.x, v1 = acc[r][1] + bb.y;
            float v2 = acc[r][2] + bb.z, v3 = acc[r][3] + bb.w;
            if (RELU) { v0 = fmaxf(v0, 0.f); v1 = fmaxf(v1, 0.f); v2 = fmaxf(v2, 0.f); v3 = fmaxf(v3, 0.f); }
            unsigned b01 = (unsigned)f2bf(v0) | ((unsigned)f2bf(v1) << 16);
            unsigned b23 = (unsigned)f2bf(v2) | ((unsigned)f2bf(v3) << 16);
            *(uint2*)(h1b + (size_t)gr * NCOL + cols) = make_uint2(b01, b23);
            double pd[8];
#pragma unroll
            for (int e = 0; e < 8; ++e)
                pd[e] = (double)v0 * (double)wreg[0][e] + (double)v1 * (double)wreg[1][e]
                      + (double)v2 * (double)wreg[2][e] + (double)v3 * (double)wreg[3][e];
#pragma unroll
            for (int e = 0; e < 8; ++e)
#pragma unroll
                for (int off = 1; off < 64; off <<= 1) pd[e] += __shfl_xor(pd[e], off);
            if (lane == 0) {
#pragma unroll
                for (int e = 0; e < 8; ++e) G2[(size_t)gr * 8 + e] = pd[e];
            }
        }
    }
}

// ---------------- MFMA GEMM (layers 2/3). MODE 0: fp32 A -> f2bf in LDS.
// MODE 2: A already bf16, direct stage. MODE 9: half skipped entirely.
template<int DIN, int MODE, int CT>
DEV void gemm_half(const void* __restrict__ Asrc, const unsigned short* __restrict__ BT,
                   short (*Ah)[40], short (*Bs)[40],
                   const int* rows, f32x4 (&acc)[4][CT], int t, int lane, int w) {
    if (MODE == 9) return;
    int q = lane >> 4, m16 = lane & 15;
    int r = t >> 2, part = t & 3;
    for (int kc = 0; kc < DIN; kc += 32) {
        __syncthreads();
        if (MODE == 2) {
            *(uint4*)&Ah[r][part * 8] =
                *(const uint4*)((const unsigned short*)Asrc + (size_t)rows[r] * DIN + kc + part * 8);
        } else {
            const float* pf = (const float*)Asrc + (size_t)rows[r] * DIN + kc + part * 8;
            float4 p0 = *(const float4*)pf, p1 = *(const float4*)(pf + 4);
            float va[8] = { p0.x, p0.y, p0.z, p0.w, p1.x, p1.y, p1.z, p1.w };
            short8 h;
#pragma unroll
            for (int j = 0; j < 8; ++j) h[j] = (short)f2bf(va[j]);
            *(short8*)&Ah[r][part * 8] = h;
        }
#pragma unroll
        for (int j = 0; j < CT; ++j) {
            int c = t + 256 * j;
            int nn = c >> 2, pp = c & 3;
            *(uint4*)&Bs[nn][pp * 8] = *(const uint4*)(BT + (size_t)nn * DIN + kc + pp * 8);
        }
        __syncthreads();
        short8 af[4], bfr[CT];
#pragma unroll
        for (int rt = 0; rt < 4; ++rt) af[rt] = *(short8*)&Ah[rt * 16 + m16][q * 8];
#pragma unroll
        for (int ct = 0; ct < CT; ++ct) bfr[ct] = *(short8*)&Bs[w * CT * 16 + ct * 16 + m16][q * 8];
#pragma unroll
        for (int rt = 0; rt < 4; ++rt)
#pragma unroll
            for (int ct = 0; ct < CT; ++ct)
                acc[rt][ct] = __builtin_amdgcn_mfma_f32_16x16x32_bf16(af[rt], bfr[ct], acc[rt][ct], 0, 0, 0);
    }
}

// OUTMODE: 0 = fp32 store, 1 = bf16 store, 2 = split (cols<128 -> bf16 outp stride 128,
// cols>=128 -> fp32 outp2 stride 128; bias carries [0|bl3])
template<int DIN, int M0, int M1, int CT, bool EXPERT, bool RELU, int OUTMODE>
__global__ __launch_bounds__(256) void k_gemm(
    const void* __restrict__ A0, const void* __restrict__ A1,
    const unsigned short* __restrict__ B0T, const unsigned short* __restrict__ B1T,
    const float* __restrict__ bias,
    const int* __restrict__ perm, const int* __restrict__ eoff,
    void* __restrict__ outp, void* __restrict__ outp2, int n) {
    constexpr int NCOL = CT * 64;
    __shared__ short Ah[64][40];
    __shared__ short Bs[NCOL][40];
    __shared__ int rows[64];
    int t = threadIdx.x;
    int lane = t & 63, w = t >> 6;
    int e = 0, base = 0, cnt = n;
    if (EXPERT) { e = blockIdx.y; base = eoff[e]; cnt = eoff[e + 1] - base; }
    int rs = blockIdx.x * 64;
    if (rs >= cnt) return;
    int nrows = min(64, cnt - rs);
    if (t < 64) {
        int j = rs + min(t, nrows - 1);
        rows[t] = EXPERT ? perm[base + j] : j;
    }
    __syncthreads();
    f32x4 acc[4][CT];
#pragma unroll
    for (int rt = 0; rt < 4; ++rt)
#pragma unroll
        for (int ct = 0; ct < CT; ++ct) acc[rt][ct] = (f32x4)(0.f);

    gemm_half<DIN, M0, CT>(A0, B0T + (EXPERT ? (size_t)e * DIN * NCOL : 0), Ah, Bs, rows, acc, t, lane, w);
    gemm_half<DIN, M1, CT>(A1, B1T, Ah, Bs, rows, acc, t, lane, w);

    int q = lane >> 4, m16 = lane & 15;
#pragma unroll
    for (int ct = 0; ct < CT; ++ct) {
        int col = w * CT * 16 + ct * 16 + m16;
        float bv = bias[(EXPERT ? e * NCOL : 0) + col];
#pragma unroll
        for (int rt = 0; rt < 4; ++rt)
#pragma unroll
            for (int i = 0; i < 4; ++i) {
                int rr = rt * 16 + q * 4 + i;
                if (rr < nrows) {
                    int gr = rows[rr];
                    float v = acc[rt][ct][i] + bv;
                    if (RELU) v = fmaxf(v, 0.f);
                    if (OUTMODE == 1) ((unsigned short*)outp)[(size_t)gr * NCOL + col] = f2bf(v);
                    else if (OUTMODE == 0) ((float*)outp)[(size_t)gr * NCOL + col] = v;
                    else {
                        if (col < 128) ((unsigned short*)outp)[(size_t)gr * 128 + col] = f2bf(v);
                        else           ((float*)outp2)[(size_t)gr * 128 + (col - 128)] = v;
                    }
                }
            }
    }
}

__global__ void k_final(const float* __restrict__ gsum, float* __restrict__ outf) {
    if (threadIdx.x == 0 && blockIdx.x == 0) {
        float g = (gsum[0] + gsum[1]) * (0.5f / 50000.0f);
        outf[(size_t)50000 * 128] = g;   // output buffer is fp32
    }
}

extern "C" void kernel_launch(void* const* d_in, const int* in_sizes, int n_in,
                              void* d_out, int out_size, void* d_ws, size_t ws_size,
                              hipStream_t stream) {
    constexpr int N = 50000, E = 800000;
    const float* x   = (const float*)d_in[0];
    const int* ei    = (const int*)d_in[1];
    const float* wg1 = (const float*)d_in[2];
    const float* bg1 = (const float*)d_in[3];
    const float* we1 = (const float*)d_in[4];
    const float* be1 = (const float*)d_in[5];
    const float* wr1 = (const float*)d_in[6];
    const float* wg2 = (const float*)d_in[7];
    const float* bg2 = (const float*)d_in[8];
    const float* we2 = (const float*)d_in[9];
    const float* be2 = (const float*)d_in[10];
    const float* wr2 = (const float*)d_in[11];
    const float* wl3 = (const float*)d_in[12];
    const float* bl3 = (const float*)d_in[13];
    const float* wr3 = (const float*)d_in[14];

    // ---- workspace layout ----
    int* ip = (int*)d_ws;
    int* deg = ip;            ip += N;
    int* cursor = ip;         ip += N;
    int* ecnt = ip;           ip += 16;
    int* ecur = ip;           ip += 16;
    float* gsum = (float*)ip; ip += 2;
    int* flags = ip;          ip += 2;
    float* bias3 = (float*)ip; ip += 256;
    int* row_ptr = ip;        ip += N + 1;
    int* csr = ip;            ip += E;
    int* idxb = ip;           ip += N;
    int* permb = ip;          ip += N;
    int* eoff = ip;           ip += 18;
    int* part = ip;           ip += 256;
    int* src32 = ip;          ip += E;
    int* dst32 = ip;          ip += E;
    size_t off = (size_t)((char*)ip - (char*)d_ws);
    off = (off + 255) & ~(size_t)255;
    float* fp = (float*)((char*)d_ws + off);
    double* G2 = (double*)fp; fp += (size_t)N * 16;    // fp64 [N][8] gate-2 pre-logits
    float* agg = fp; fp += (size_t)N * 256;            // fp32 agg (layer 1); bf16 aggb (layer 2); Rf (layer 3)
    float* h1  = fp; fp += (size_t)N * 256;            // bf16 h1b (first half); Pb (second half)
    unsigned short* wp = (unsigned short*)fp;
    unsigned short* h2b  = wp; wp += (size_t)N * 256;  // bf16 h2 (gate-free)
    unsigned short* we2T = wp; wp += 8 * 256 * 256;    // bf16 B^T [n][k]
    unsigned short* wr2T = wp; wp += 256 * 256;
    unsigned short* wl3T = wp; wp += 256 * 128;
    unsigned short* wr3T = wp; wp += 256 * 128;
    unsigned short* aggb = (unsigned short*)agg;       // bf16 [N][256] (aliases agg; layer-2 A)
    unsigned short* h1b  = (unsigned short*)h1;        // bf16 [N][256]
    unsigned short* Pb = (unsigned short*)(h1 + (size_t)N * 128);  // bf16 [N][128], 2nd half of h1 region
    float* Rf = agg;                                   // fp32 [N][128] (aggb dead by layer-3)

    hipMemsetAsync(d_ws, 0, (size_t)(2 * N + 36) * 4, stream);

    k_detect<<<1, 64, 0, stream>>>(ei, flags);
    k_cvt_idx<<<(E + 255) / 256, 256, 0, stream>>>(ei, src32, dst32, deg, E, flags);

    // fused transpose+narrow to bf16 B^T [n][k] (layers 2/3)
    k_transpose_nb<<<dim3(8, 8, 8), 256, 0, stream>>>(we2, we2T, 256, 256);
    k_transpose_nb<<<dim3(8, 8, 1), 256, 0, stream>>>(wr2, wr2T, 256, 256);
    k_transpose_nb<<<dim3(4, 8, 1), 256, 0, stream>>>(wl3, wl3T, 256, 128);
    k_transpose_nb<<<dim3(4, 8, 1), 256, 0, stream>>>(wr3, wr3T, 256, 128);
    k_bias3<<<1, 256, 0, stream>>>(bl3, bias3);

    // CSR (degree fused into k_cvt_idx)
    constexpr int NB = (N + 255) / 256;
    constexpr int WB = (N + 3) / 4;
    k_scan1<<<NB, 256, 0, stream>>>(deg, row_ptr, part, N);
    k_scan2<<<1, 256, 0, stream>>>(part, NB);
    k_scan3<<<NB, 256, 0, stream>>>(row_ptr, part, N, E);
    k_fill<<<(E + 255) / 256, 256, 0, stream>>>(src32, dst32, row_ptr, cursor, csr, E);

    constexpr int GB = (N + 63) / 64;      // 64-row tiles (MFMA layers 2/3)
    constexpr int GB32 = (N + 31) / 32;    // 32-row tiles (VALU layer 1, compact grid)
    // ---- layer 1: 128 -> 256, MoE + root(x), relu — VALU fp32; h1b bf16 + G2 fp64 out ----
    k_aggr<128><<<WB, 256, 0, stream>>>(x, row_ptr, csr, agg, N);
    k_gate<128><<<NB, 256, 0, stream>>>(agg, wg1, bg1, idxb, ecnt, gsum, N);
    k_offsets<<<1, 1, 0, stream>>>(ecnt, eoff);
    k_perm<<<NB, 256, 0, stream>>>(idxb, eoff, ecur, permb, N);
    k_gemm_f32<128, 256, true><<<dim3(GB32), 256, 0, stream>>>(
        agg, x, we1, wr1, be1, wg2, permb, eoff, h1b, G2, N);

    // ---- layer 2: 256 -> 256, MoE + root(h1), relu — gate from G2; bf16 gather; MODE-2 GEMM ----
    k_gate_g<<<NB, 256, 0, stream>>>(G2, row_ptr, csr, bg2, idxb, ecnt + 8, gsum + 1, N);
    k_aggr_h1b<<<WB, 256, 0, stream>>>(h1b, row_ptr, csr, aggb, N);
    k_offsets<<<1, 1, 0, stream>>>(ecnt + 8, eoff + 9);
    k_perm<<<NB, 256, 0, stream>>>(idxb, eoff + 9, ecur + 8, permb, N);
    k_gemm<256, 2, 2, 4, true, true, 1><<<dim3(GB, 8), 256, 0, stream>>>(
        aggb, h1b, we2T, wr2T, be2, permb, eoff + 9, h2b, nullptr, N);

    // ---- layer 3 (linearity swap): [P|R] = h2b @ [wl3|wr3]; out = mean_aggr(P) + R ----
    k_gemm<256, 2, 9, 4, false, false, 2><<<dim3(GB, 1), 256, 0, stream>>>(
        h2b, nullptr, wl3T, nullptr, bias3, nullptr, nullptr, Pb, Rf, N);
    k_aggr_badd<<<WB, 256, 0, stream>>>(Pb, row_ptr, csr, Rf, (float*)d_out, N);

    k_final<<<1, 1, 0, stream>>>(gsum, (float*)d_out);
}

// Round 10
// 620.027 us; speedup vs baseline: 1.0848x; 1.0391x over previous
//
#include <hip/hip_runtime.h>
#include <hip/hip_bf16.h>
#include <stdint.h>

#define DEV static __device__ __forceinline__

typedef __attribute__((ext_vector_type(8))) short short8;   // 8 bf16 (4 VGPRs)
typedef __attribute__((ext_vector_type(4))) float f32x4;    // MFMA accumulator

DEV float bf2f(unsigned short u) { return __uint_as_float(((unsigned)u) << 16); }
DEV float bflo(unsigned u) { return __uint_as_float(u << 16); }
DEV float bfhi(unsigned u) { return __uint_as_float(u & 0xffff0000u); }
DEV unsigned short f2bf(float f) {
    unsigned u = __float_as_uint(f);
    u += 0x7fff + ((u >> 16) & 1);   // RNE
    return (unsigned short)(u >> 16);
}

// ---------------- edge_index width detection (int64 vs int32) ----------------
__global__ void k_detect(const int* __restrict__ ei, int* __restrict__ flags) {
    if (threadIdx.x == 0 && blockIdx.x == 0) {
        int zeros = 0;
        for (int i = 0; i < 128; ++i) if (ei[2 * i + 1] == 0) ++zeros;
        flags[1] = (zeros >= 64) ? 1 : 0;
    }
}

// fused: index narrow + degree count (saves a separate 800k-element pass)
__global__ void k_cvt_idx(const int* __restrict__ ei, int* __restrict__ src32,
                          int* __restrict__ dst32, int* __restrict__ deg,
                          int E, const int* __restrict__ flags) {
    int i = blockIdx.x * 256 + threadIdx.x;
    if (i >= E) return;
    int s, d;
    if (flags[1]) { s = ei[2 * i]; d = ei[2 * E + 2 * i]; }
    else          { s = ei[i];     d = ei[E + i]; }
    src32[i] = s; dst32[i] = d;
    atomicAdd(&deg[d], 1);
}

// ---------------- fused transpose+narrow: fp32 in[r][c] -> bf16 out[c][r] ----------------
__global__ void k_transpose_nb(const float* __restrict__ in, unsigned short* __restrict__ out,
                               int R, int C) {
    __shared__ unsigned short tile[32][33];
    int tx = threadIdx.x & 31, ty = threadIdx.x >> 5;   // 256 threads = 32x8
    size_t mat = (size_t)blockIdx.z * R * C;
    int r0 = blockIdx.y * 32, c0 = blockIdx.x * 32;
#pragma unroll
    for (int j = 0; j < 32; j += 8)
        tile[ty + j][tx] = f2bf(in[mat + (size_t)(r0 + ty + j) * C + c0 + tx]);
    __syncthreads();
#pragma unroll
    for (int j = 0; j < 32; j += 8)
        out[mat + (size_t)(c0 + ty + j) * R + r0 + tx] = tile[tx][ty + j];
}

// bias for the fused layer-3 GEMM: cols 0..127 (P half) get 0, cols 128..255 get bl3
__global__ void k_bias3(const float* __restrict__ bl3, float* __restrict__ bias3) {
    int t = threadIdx.x;
    bias3[t] = (t < 128) ? 0.f : bl3[t - 128];
}

// ---------------- CSR build: degree (fused above) -> 3-phase shfl scan -> fill ----------------
__global__ void k_scan1(const int* __restrict__ deg, int* __restrict__ row_ptr,
                        int* __restrict__ part, int n) {
    __shared__ int wsum[4];
    int t = threadIdx.x, lane = t & 63, wv = t >> 6;
    int i = blockIdx.x * 256 + t;
    int v0 = (i < n) ? deg[i] : 0;
    int v = v0;
#pragma unroll
    for (int d = 1; d < 64; d <<= 1) { int u = __shfl_up(v, d); if (lane >= d) v += u; }
    if (lane == 63) wsum[wv] = v;
    __syncthreads();
    int add = 0;
    for (int w2 = 0; w2 < wv; ++w2) add += wsum[w2];
    v += add;
    if (i < n) row_ptr[i] = v - v0;            // block-local exclusive
    if (t == 255) part[blockIdx.x] = v;        // block total
}

__global__ void k_scan2(int* __restrict__ part, int P) {
    __shared__ int wsum[4];
    int t = threadIdx.x, lane = t & 63, wv = t >> 6;
    int v0 = (t < P) ? part[t] : 0;
    int v = v0;
#pragma unroll
    for (int d = 1; d < 64; d <<= 1) { int u = __shfl_up(v, d); if (lane >= d) v += u; }
    if (lane == 63) wsum[wv] = v;
    __syncthreads();
    int add = 0;
    for (int w2 = 0; w2 < wv; ++w2) add += wsum[w2];
    v += add;
    if (t < P) part[t] = v - v0;               // exclusive over partials
}

__global__ void k_scan3(int* __restrict__ row_ptr, const int* __restrict__ part, int n, int E) {
    int i = blockIdx.x * 256 + threadIdx.x;
    if (i < n) row_ptr[i] += part[blockIdx.x];
    if (i == 0) row_ptr[n] = E;
}

__global__ void k_fill(const int* __restrict__ src, const int* __restrict__ dst,
                       const int* __restrict__ row_ptr, int* __restrict__ cursor,
                       int* __restrict__ csr, int E) {
    int i = blockIdx.x * 256 + threadIdx.x;
    if (i < E) {
        int d = dst[i];
        int p = atomicAdd(&cursor[d], 1);
        csr[row_ptr[d] + p] = src[i];
    }
}
// NOTE (round-16): per-list src sort tried — FETCH unchanged, +94 us. Reverted.
// NOTE (round-17): compact-grid MFMA MoE GEMM tried — +18 us. Chaff blocks in
// dim3(GB,8) exit before any barrier; dispatch drain is ~free. Reverted.
// NOTE (round-18): 8-row unroll on the gather: +3% only — bandwidth-proportional.
// NOTE (round-19): fp64 shfl-tree G2 epilogue cost +46 us in k_gemm_f32 ->
// round-20 switches to fp32 partials + 2-phase (27-shfl) reduction.

// ---------------- mean aggregation: one wave/node, fp64 accumulate, 8-row unroll ----------------
template<int D>
__global__ __launch_bounds__(256, 2) void k_aggr(
    const float* __restrict__ xin, const int* __restrict__ row_ptr,
    const int* __restrict__ csr, float* __restrict__ agg, int n) {
    int wid = (blockIdx.x * blockDim.x + threadIdx.x) >> 6;
    int lane = threadIdx.x & 63;
    if (wid >= n) return;
    constexpr int V = D / 64;
    double ac[8][V];
#pragma unroll
    for (int r = 0; r < 8; ++r)
#pragma unroll
        for (int i = 0; i < V; ++i) ac[r][i] = 0.0;
    int s0 = row_ptr[wid], s1 = row_ptr[wid + 1];
    int j = s0;
    for (; j + 8 <= s1; j += 8) {
        const float* p[8];
#pragma unroll
        for (int r = 0; r < 8; ++r) p[r] = xin + (size_t)csr[j + r] * D + lane * V;
        if (V == 2) {
            float2 f[8];
#pragma unroll
            for (int r = 0; r < 8; ++r) f[r] = *(const float2*)p[r];
#pragma unroll
            for (int r = 0; r < 8; ++r) { ac[r][0] += (double)f[r].x; ac[r][1] += (double)f[r].y; }
        } else {
            float4 f[8];
#pragma unroll
            for (int r = 0; r < 8; ++r) f[r] = *(const float4*)p[r];
#pragma unroll
            for (int r = 0; r < 8; ++r) {
                ac[r][0] += (double)f[r].x; ac[r][1] += (double)f[r].y;
                ac[r][2] += (double)f[r].z; ac[r][3] += (double)f[r].w;
            }
        }
    }
    for (; j + 4 <= s1; j += 4) {
        const float* p[4];
#pragma unroll
        for (int r = 0; r < 4; ++r) p[r] = xin + (size_t)csr[j + r] * D + lane * V;
        if (V == 2) {
            float2 f[4];
#pragma unroll
            for (int r = 0; r < 4; ++r) f[r] = *(const float2*)p[r];
#pragma unroll
            for (int r = 0; r < 4; ++r) { ac[r][0] += (double)f[r].x; ac[r][1] += (double)f[r].y; }
        } else {
            float4 f[4];
#pragma unroll
            for (int r = 0; r < 4; ++r) f[r] = *(const float4*)p[r];
#pragma unroll
            for (int r = 0; r < 4; ++r) {
                ac[r][0] += (double)f[r].x; ac[r][1] += (double)f[r].y;
                ac[r][2] += (double)f[r].z; ac[r][3] += (double)f[r].w;
            }
        }
    }
    for (; j < s1; ++j) {
        const float* p = xin + (size_t)csr[j] * D + lane * V;
        if (V == 2) {
            float2 f = *(const float2*)p;
            ac[0][0] += (double)f.x; ac[0][1] += (double)f.y;
        } else {
            float4 f = *(const float4*)p;
            ac[0][0] += (double)f.x; ac[0][1] += (double)f.y;
            ac[0][2] += (double)f.z; ac[0][3] += (double)f.w;
        }
    }
    double inv = 1.0 / (double)max(s1 - s0, 1);
#pragma unroll
    for (int i = 0; i < V; ++i) {
        double s = ((ac[0][i] + ac[1][i]) + (ac[2][i] + ac[3][i]))
                 + ((ac[4][i] + ac[5][i]) + (ac[6][i] + ac[7][i]));
        agg[(size_t)wid * D + lane * V + i] = (float)(s * inv);
    }
}

// Layer-2 gather: reads bf16 h1b (512 B/row, half the fp32 bytes), writes bf16 agg
// for the MODE-2 GEMM stage. Gate-2 no longer depends on this (G2 path).
__global__ __launch_bounds__(256, 2) void k_aggr_h1b(
    const unsigned short* __restrict__ xin, const int* __restrict__ row_ptr,
    const int* __restrict__ csr, unsigned short* __restrict__ aggb, int n) {
    int wid = (blockIdx.x * blockDim.x + threadIdx.x) >> 6;
    int lane = threadIdx.x & 63;
    if (wid >= n) return;
    double ac[8][4];
#pragma unroll
    for (int r = 0; r < 8; ++r)
#pragma unroll
        for (int i = 0; i < 4; ++i) ac[r][i] = 0.0;
    int s0 = row_ptr[wid], s1 = row_ptr[wid + 1];
    int j = s0;
    for (; j + 8 <= s1; j += 8) {
        uint2 u[8];
#pragma unroll
        for (int r = 0; r < 8; ++r) u[r] = *(const uint2*)(xin + (size_t)csr[j + r] * 256 + lane * 4);
#pragma unroll
        for (int r = 0; r < 8; ++r) {
            ac[r][0] += (double)bflo(u[r].x); ac[r][1] += (double)bfhi(u[r].x);
            ac[r][2] += (double)bflo(u[r].y); ac[r][3] += (double)bfhi(u[r].y);
        }
    }
    for (; j + 4 <= s1; j += 4) {
        uint2 u[4];
#pragma unroll
        for (int r = 0; r < 4; ++r) u[r] = *(const uint2*)(xin + (size_t)csr[j + r] * 256 + lane * 4);
#pragma unroll
        for (int r = 0; r < 4; ++r) {
            ac[r][0] += (double)bflo(u[r].x); ac[r][1] += (double)bfhi(u[r].x);
            ac[r][2] += (double)bflo(u[r].y); ac[r][3] += (double)bfhi(u[r].y);
        }
    }
    for (; j < s1; ++j) {
        uint2 u = *(const uint2*)(xin + (size_t)csr[j] * 256 + lane * 4);
        ac[0][0] += (double)bflo(u.x); ac[0][1] += (double)bfhi(u.x);
        ac[0][2] += (double)bflo(u.y); ac[0][3] += (double)bfhi(u.y);
    }
    double inv = 1.0 / (double)max(s1 - s0, 1);
    float m[4];
#pragma unroll
    for (int i = 0; i < 4; ++i) {
        double s = ((ac[0][i] + ac[1][i]) + (ac[2][i] + ac[3][i]))
                 + ((ac[4][i] + ac[5][i]) + (ac[6][i] + ac[7][i]));
        m[i] = (float)(s * inv);
    }
    unsigned b01 = (unsigned)f2bf(m[0]) | ((unsigned)f2bf(m[1]) << 16);
    unsigned b23 = (unsigned)f2bf(m[2]) | ((unsigned)f2bf(m[3]) << 16);
    *(uint2*)(aggb + (size_t)wid * 256 + lane * 4) = make_uint2(b01, b23);
}

// Layer-3 fused gather (8-row unroll): P is bf16 [n][128]; out = mean(P[nbrs]) + R.
__global__ __launch_bounds__(256, 2) void k_aggr_badd(
    const unsigned short* __restrict__ Pb, const int* __restrict__ row_ptr,
    const int* __restrict__ csr, const float* __restrict__ Rf,
    float* __restrict__ outp, int n) {
    int wid = (blockIdx.x * blockDim.x + threadIdx.x) >> 6;
    int lane = threadIdx.x & 63;
    if (wid >= n) return;
    double ac[8][2];
#pragma unroll
    for (int r = 0; r < 8; ++r) { ac[r][0] = 0.0; ac[r][1] = 0.0; }
    int s0 = row_ptr[wid], s1 = row_ptr[wid + 1];
    int j = s0;
    for (; j + 8 <= s1; j += 8) {
        unsigned u[8];
#pragma unroll
        for (int r = 0; r < 8; ++r) u[r] = *(const unsigned*)(Pb + (size_t)csr[j + r] * 128 + lane * 2);
#pragma unroll
        for (int r = 0; r < 8; ++r) { ac[r][0] += (double)bflo(u[r]); ac[r][1] += (double)bfhi(u[r]); }
    }
    for (; j + 4 <= s1; j += 4) {
        unsigned u[4];
#pragma unroll
        for (int r = 0; r < 4; ++r) u[r] = *(const unsigned*)(Pb + (size_t)csr[j + r] * 128 + lane * 2);
#pragma unroll
        for (int r = 0; r < 4; ++r) { ac[r][0] += (double)bflo(u[r]); ac[r][1] += (double)bfhi(u[r]); }
    }
    for (; j < s1; ++j) {
        unsigned u = *(const unsigned*)(Pb + (size_t)csr[j] * 128 + lane * 2);
        ac[0][0] += (double)bflo(u); ac[0][1] += (double)bfhi(u);
    }
    double inv = 1.0 / (double)max(s1 - s0, 1);
    float2 r2 = *(const float2*)(Rf + (size_t)wid * 128 + lane * 2);
    float2 o;
    o.x = (float)((((ac[0][0] + ac[1][0]) + (ac[2][0] + ac[3][0]))
                 + ((ac[4][0] + ac[5][0]) + (ac[6][0] + ac[7][0]))) * inv) + r2.x;
    o.y = (float)((((ac[0][1] + ac[1][1]) + (ac[2][1] + ac[3][1]))
                 + ((ac[4][1] + ac[5][1]) + (ac[6][1] + ac[7][1]))) * inv) + r2.y;
    *(float2*)(outp + (size_t)wid * 128 + lane * 2) = o;
}

// ---------------- gate-1 (round-5 verbatim; fp32 weights read directly) ----------------
template<int D>
__global__ void k_gate(const float* __restrict__ agg, const float* __restrict__ wg,
                       const float* __restrict__ bg, int* __restrict__ idx,
                       int* __restrict__ ecnt, float* __restrict__ gsum, int n) {
    __shared__ float swg[D * 8];
    __shared__ int hcnt[8];
    __shared__ float red[256];
    int t = threadIdx.x;
    if (t < 8) hcnt[t] = 0;
    for (int i = t; i < D * 8; i += 256) swg[i] = wg[i];
    __syncthreads();
    int nid = blockIdx.x * 256 + t;
    float stdv = 0.f;
    if (nid < n) {
        double lg[8];
#pragma unroll
        for (int e = 0; e < 8; ++e) lg[e] = (double)bg[e];
        const float* ap = agg + (size_t)nid * D;
        for (int k = 0; k < D; k += 4) {
            float4 a = *(const float4*)(ap + k);
#pragma unroll
            for (int e = 0; e < 8; ++e) {
                lg[e] += (double)a.x * swg[(k + 0) * 8 + e] + (double)a.y * swg[(k + 1) * 8 + e]
                       + (double)a.z * swg[(k + 2) * 8 + e] + (double)a.w * swg[(k + 3) * 8 + e];
            }
        }
        double m = lg[0];
        int am = 0;
#pragma unroll
        for (int e = 1; e < 8; ++e) if (lg[e] > m) { m = lg[e]; am = e; }
        double s = 0.0, p[8];
#pragma unroll
        for (int e = 0; e < 8; ++e) { p[e] = exp(lg[e] - m); s += p[e]; }
        double invs = 1.0 / s, sq = 0.0;
#pragma unroll
        for (int e = 0; e < 8; ++e) { double q = p[e] * invs; sq += q * q; }
        stdv = (float)sqrt(fmax(sq - 0.125, 0.0) / 7.0);
        idx[nid] = am;
        atomicAdd(&hcnt[am], 1);
    }
    red[t] = stdv;
    __syncthreads();
    for (int off = 128; off > 0; off >>= 1) {
        if (t < off) red[t] += red[t + off];
        __syncthreads();
    }
    if (t == 0) atomicAdd(gsum, red[0]);
    if (t < 8 && hcnt[t] > 0) atomicAdd(&ecnt[t], hcnt[t]);
}

// ---------------- gate-2 from G2 (fp32 [N][8], linearity swap) ----------------
// logits2 = mean(relu(h1) @ wg2) + bg2. G2 1.6 MB, L2-resident. fp64 mean accum.
__global__ void k_gate_g(const float* __restrict__ G2, const int* __restrict__ row_ptr,
                         const int* __restrict__ csr, const float* __restrict__ bg,
                         int* __restrict__ idx, int* __restrict__ ecnt,
                         float* __restrict__ gsum, int n) {
    __shared__ int hcnt[8];
    __shared__ float red[256];
    int t = threadIdx.x;
    if (t < 8) hcnt[t] = 0;
    __syncthreads();
    int nid = blockIdx.x * 256 + t;
    float stdv = 0.f;
    if (nid < n) {
        double lg[8];
#pragma unroll
        for (int e = 0; e < 8; ++e) lg[e] = 0.0;
        int s0 = row_ptr[nid], s1 = row_ptr[nid + 1];
        for (int j = s0; j < s1; ++j) {
            const float* g = G2 + (size_t)csr[j] * 8;
            float4 g0 = *(const float4*)g, g1 = *(const float4*)(g + 4);
            lg[0] += (double)g0.x; lg[1] += (double)g0.y; lg[2] += (double)g0.z; lg[3] += (double)g0.w;
            lg[4] += (double)g1.x; lg[5] += (double)g1.y; lg[6] += (double)g1.z; lg[7] += (double)g1.w;
        }
        double inv = 1.0 / (double)max(s1 - s0, 1);
#pragma unroll
        for (int e = 0; e < 8; ++e) lg[e] = lg[e] * inv + (double)bg[e];
        double m = lg[0];
        int am = 0;
#pragma unroll
        for (int e = 1; e < 8; ++e) if (lg[e] > m) { m = lg[e]; am = e; }
        double s = 0.0, p[8];
#pragma unroll
        for (int e = 0; e < 8; ++e) { p[e] = exp(lg[e] - m); s += p[e]; }
        double invs = 1.0 / s, sq = 0.0;
#pragma unroll
        for (int e = 0; e < 8; ++e) { double q = p[e] * invs; sq += q * q; }
        stdv = (float)sqrt(fmax(sq - 0.125, 0.0) / 7.0);
        idx[nid] = am;
        atomicAdd(&hcnt[am], 1);
    }
    red[t] = stdv;
    __syncthreads();
    for (int off = 128; off > 0; off >>= 1) {
        if (t < off) red[t] += red[t + off];
        __syncthreads();
    }
    if (t == 0) atomicAdd(gsum, red[0]);
    if (t < 8 && hcnt[t] > 0) atomicAdd(&ecnt[t], hcnt[t]);
}

__global__ void k_offsets(const int* __restrict__ ecnt, int* __restrict__ eoff) {
    if (threadIdx.x == 0 && blockIdx.x == 0) {
        int s = 0;
        for (int e = 0; e < 8; ++e) { eoff[e] = s; s += ecnt[e]; }
        eoff[8] = s;
    }
}

__global__ void k_perm(const int* __restrict__ idx, const int* __restrict__ eoff,
                       int* __restrict__ ecur, int* __restrict__ perm, int n) {
    __shared__ int lcnt[8], lbase[8];
    int t = threadIdx.x;
    if (t < 8) lcnt[t] = 0;
    __syncthreads();
    int nid = blockIdx.x * 256 + t;
    int e = 0, r = 0;
    bool valid = (nid < n);
    if (valid) { e = idx[nid]; r = atomicAdd(&lcnt[e], 1); }
    __syncthreads();
    if (t < 8) lbase[t] = lcnt[t] ? atomicAdd(&ecur[t], lcnt[t]) : 0;
    __syncthreads();
    if (valid) perm[eoff[e] + lbase[e] + r] = nid;
}

// ---------------- VALU fp32 GEMM, layer 1 (compact grid; h1 VALUES bit-identical) ----
// Epilogue: (a) h1 stored bf16 (h1b) — identical bits to the layer-2 stage f2bf.
// (b) G2[row][e] = relu(h1_row) @ wg2: round-20 = fp32 partials + 2-phase reduce
// (27 shfls/row vs 48 fp64). Error class ~5e-8 on logits — same as the fp32-agg
// path that passed rounds 0-8 (cliff ~1e-6).
template<int NCOL, bool LOAD>
DEV void g_step(int g, const float* __restrict__ Bp, const float* __restrict__ at,
                float4 (&cur)[4], float (&acc)[8][4]) {
    float bx[4][4];
#pragma unroll
    for (int kk = 0; kk < 4; ++kk) {
        bx[kk][0] = cur[kk].x; bx[kk][1] = cur[kk].y;
        bx[kk][2] = cur[kk].z; bx[kk][3] = cur[kk].w;
    }
#pragma unroll
    for (int r = 0; r < 8; ++r) {
        float4 a = *(const float4*)(at + r * 68 + g * 4);   // uniform addr -> LDS broadcast
#pragma unroll
        for (int c = 0; c < 4; ++c) {
            acc[r][c] = fmaf(a.x, bx[0][c], acc[r][c]);
            acc[r][c] = fmaf(a.y, bx[1][c], acc[r][c]);
            acc[r][c] = fmaf(a.z, bx[2][c], acc[r][c]);
            acc[r][c] = fmaf(a.w, bx[3][c], acc[r][c]);
        }
    }
    if (LOAD) {
#pragma unroll
        for (int kk = 0; kk < 4; ++kk)
            cur[kk] = *(const float4*)(Bp + (size_t)(g * 4 + 8 + kk) * NCOL);
    }
}

template<int NCOL>
DEV void compute_chunk(const float* __restrict__ Bp, const float* __restrict__ at,
                       float (&acc)[8][4]) {
    float4 bA[4], bB[4];
#pragma unroll
    for (int kk = 0; kk < 4; ++kk) bA[kk] = *(const float4*)(Bp + (size_t)kk * NCOL);
#pragma unroll
    for (int kk = 0; kk < 4; ++kk) bB[kk] = *(const float4*)(Bp + (size_t)(4 + kk) * NCOL);
#pragma unroll 1
    for (int g = 0; g < 14; g += 2) {          // rolled: keep body ~2.5 KB for I$
        g_step<NCOL, true>(g, Bp, at, bA, acc);
        g_step<NCOL, true>(g + 1, Bp, at, bB, acc);
    }
    g_step<NCOL, false>(14, Bp, at, bA, acc);
    g_step<NCOL, false>(15, Bp, at, bB, acc);
}

template<int DIN, int NCOL, bool RELU>
__global__ __launch_bounds__(256, 4) void k_gemm_f32(
    const float* __restrict__ agg, const float* __restrict__ a2,
    const float* __restrict__ B1, const float* __restrict__ B2,
    const float* __restrict__ bias, const float* __restrict__ wg2,
    const int* __restrict__ perm, const int* __restrict__ eoff,
    unsigned short* __restrict__ h1b, float* __restrict__ G2, int n) {
    static_assert(DIN == 128 && NCOL == 256, "layer-1 geometry");
    __shared__ float a_tile[2][4 * 8 * 68];
    __shared__ int rows[32];
    int t = threadIdx.x;
    int rs = blockIdx.x * 32;
    if (rs >= n) return;
    int nrows = min(32, n - rs);
    if (t < 32) rows[t] = perm[rs + min(t, nrows - 1)];
    __syncthreads();                            // the only barrier in this kernel

    int e0 = 0, e1 = 0;
    int last = rs + nrows - 1;
#pragma unroll
    for (int e = 1; e < 8; ++e) {
        int v = eoff[e];
        if (v <= rs) e0 = e;
        if (v <= last) e1 = e;
    }
    int ne = e1 - e0 + 1;
    int nchunks = 2 * ne + 2;

    int lane = t & 63, rg = t >> 6;
    int cols = lane * 4;
    int srow = lane >> 3;                       // 0..7 within wave
    int sk = (lane & 7) * 8;                    // 0..56
    int gpos = rs + rg * 8 + srow;              // global perm position of my staged row
    int myrow = rows[rg * 8 + srow];
    float* stc = &a_tile[0][rg * 544 + srow * 68 + sk];
    float* stn = &a_tile[1][rg * 544 + srow * 68 + sk];
    const float* atc = &a_tile[0][rg * 544];
    const float* atn = &a_tile[1][rg * 544];

    float acc[8][4];
#pragma unroll
    for (int r = 0; r < 8; ++r) { acc[r][0] = 0.f; acc[r][1] = 0.f; acc[r][2] = 0.f; acc[r][3] = 0.f; }

    auto params = [&](int c, const float*& ap, const float*& Bp, float& m) {
        int half = c & 1;
        if (c < 2 * ne) {
            int e = e0 + (c >> 1);
            ap = agg + (size_t)myrow * DIN + sk + half * 64;
            Bp = B1 + (size_t)e * DIN * NCOL + (size_t)half * 64 * NCOL + cols;
            m = (gpos >= eoff[e] && gpos < eoff[e + 1]) ? 1.f : 0.f;
        } else {
            ap = a2 + (size_t)myrow * DIN + sk + half * 64;
            Bp = B2 + (size_t)half * 64 * NCOL + cols;
            m = 1.f;
        }
    };

    const float* ap; const float* Bp; float m;
    params(0, ap, Bp, m);
    float4 p0 = *(const float4*)ap, p1 = *(const float4*)(ap + 4);
#pragma unroll 1
    for (int c = 0; c < nchunks; ++c) {
        float4 s0 = p0, s1 = p1;
        s0.x *= m; s0.y *= m; s0.z *= m; s0.w *= m;
        s1.x *= m; s1.y *= m; s1.z *= m; s1.w *= m;
        *(float4*)stc = s0; *(float4*)(stc + 4) = s1;
        const float* Bcur = Bp;
        if (c + 1 < nchunks) {                  // prefetch next chunk's A (hidden under compute)
            params(c + 1, ap, Bp, m);
            p0 = *(const float4*)ap; p1 = *(const float4*)(ap + 4);
        }
        compute_chunk<NCOL>(Bcur, atc, acc);
        float* ts = stc; stc = stn; stn = ts;
        const float* ta = atc; atc = atn; atn = ta;
    }

    // epilogue-only wg2 registers (loaded late -> no main-loop VGPR pressure)
    float wreg[4][8];
    {
        const float* wp2 = wg2 + (size_t)cols * 8;
#pragma unroll
        for (int c = 0; c < 4; ++c) {
            float4 wa = *(const float4*)(wp2 + c * 8);
            float4 wb = *(const float4*)(wp2 + c * 8 + 4);
            wreg[c][0] = wa.x; wreg[c][1] = wa.y; wreg[c][2] = wa.z; wreg[c][3] = wa.w;
            wreg[c][4] = wb.x; wreg[c][5] = wb.y; wreg[c][6] = wb.z; wreg[c][7] = wb.w;
        }
    }
    int ksel = lane & 7;

#pragma unroll
    for (int r = 0; r < 8; ++r) {
        int rr = rg * 8 + r;                    // wave-uniform -> shfl-safe guard
        if (rr < nrows) {
            int gp = rs + rr;
            int er = e0;
            for (int e = e0 + 1; e <= e1; ++e) if (eoff[e] <= gp) er = e;
            float4 bb = *(const float4*)(bias + er * NCOL + cols);
            int gr = rows[rr];
            float v0 = acc[r][0] + bb.x, v1 = acc[r][1] + bb.y;
            float v2 = acc[r][2] + bb.z, v3 = acc[r][3] + bb.w;
            if (RELU) { v0 = fmaxf(v0, 0.f); v1 = fmaxf(v1, 0.f); v2 = fmaxf(v2, 0.f); v3 = fmaxf(v3, 0.f); }
            unsigned b01 = (unsigned)f2bf(v0) | ((unsigned)f2bf(v1) << 16);
            unsigned b23 = (unsigned)f2bf(v2) | ((unsigned)f2bf(v3) << 16);
            *(uint2*)(h1b + (size_t)gr * NCOL + cols) = make_uint2(b01, b23);
            // fp32 gate-2 partials, 2-phase butterfly reduce
            float pf[8];
#pragma unroll
            for (int e = 0; e < 8; ++e)
                pf[e] = v0 * wreg[0][e] + v1 * wreg[1][e] + v2 * wreg[2][e] + v3 * wreg[3][e];
#pragma unroll
            for (int off = 1; off < 8; off <<= 1)
#pragma unroll
                for (int e = 0; e < 8; ++e) pf[e] += __shfl_xor(pf[e], off);
            // select expert (lane&7) — compile-time chain, no scratch
            float v = pf[0];
            if (ksel == 1) v = pf[1];
            if (ksel == 2) v = pf[2];
            if (ksel == 3) v = pf[3];
            if (ksel == 4) v = pf[4];
            if (ksel == 5) v = pf[5];
            if (ksel == 6) v = pf[6];
            if (ksel == 7) v = pf[7];
#pragma unroll
            for (int off = 8; off < 64; off <<= 1) v += __shfl_xor(v, off);
            if (lane < 8) G2[(size_t)gr * 8 + lane] = v;
        }
    }
}

// ---------------- MFMA GEMM (layers 2/3). MODE 0: fp32 A -> f2bf in LDS.
// MODE 2: A already bf16, direct stage. MODE 9: half skipped entirely.
template<int DIN, int MODE, int CT>
DEV void gemm_half(const void* __restrict__ Asrc, const unsigned short* __restrict__ BT,
                   short (*Ah)[40], short (*Bs)[40],
                   const int* rows, f32x4 (&acc)[4][CT], int t, int lane, int w) {
    if (MODE == 9) return;
    int q = lane >> 4, m16 = lane & 15;
    int r = t >> 2, part = t & 3;
    for (int kc = 0; kc < DIN; kc += 32) {
        __syncthreads();
        if (MODE == 2) {
            *(uint4*)&Ah[r][part * 8] =
                *(const uint4*)((const unsigned short*)Asrc + (size_t)rows[r] * DIN + kc + part * 8);
        } else {
            const float* pf = (const float*)Asrc + (size_t)rows[r] * DIN + kc + part * 8;
            float4 p0 = *(const float4*)pf, p1 = *(const float4*)(pf + 4);
            float va[8] = { p0.x, p0.y, p0.z, p0.w, p1.x, p1.y, p1.z, p1.w };
            short8 h;
#pragma unroll
            for (int j = 0; j < 8; ++j) h[j] = (short)f2bf(va[j]);
            *(short8*)&Ah[r][part * 8] = h;
        }
#pragma unroll
        for (int j = 0; j < CT; ++j) {
            int c = t + 256 * j;
            int nn = c >> 2, pp = c & 3;
            *(uint4*)&Bs[nn][pp * 8] = *(const uint4*)(BT + (size_t)nn * DIN + kc + pp * 8);
        }
        __syncthreads();
        short8 af[4], bfr[CT];
#pragma unroll
        for (int rt = 0; rt < 4; ++rt) af[rt] = *(short8*)&Ah[rt * 16 + m16][q * 8];
#pragma unroll
        for (int ct = 0; ct < CT; ++ct) bfr[ct] = *(short8*)&Bs[w * CT * 16 + ct * 16 + m16][q * 8];
#pragma unroll
        for (int rt = 0; rt < 4; ++rt)
#pragma unroll
            for (int ct = 0; ct < CT; ++ct)
                acc[rt][ct] = __builtin_amdgcn_mfma_f32_16x16x32_bf16(af[rt], bfr[ct], acc[rt][ct], 0, 0, 0);
    }
}

// OUTMODE: 0 = fp32 store, 1 = bf16 store, 2 = split (cols<128 -> bf16 outp stride 128,
// cols>=128 -> fp32 outp2 stride 128; bias carries [0|bl3])
template<int DIN, int M0, int M1, int CT, bool EXPERT, bool RELU, int OUTMODE>
__global__ __launch_bounds__(256) void k_gemm(
    const void* __restrict__ A0, const void* __restrict__ A1,
    const unsigned short* __restrict__ B0T, const unsigned short* __restrict__ B1T,
    const float* __restrict__ bias,
    const int* __restrict__ perm, const int* __restrict__ eoff,
    void* __restrict__ outp, void* __restrict__ outp2, int n) {
    constexpr int NCOL = CT * 64;
    __shared__ short Ah[64][40];
    __shared__ short Bs[NCOL][40];
    __shared__ int rows[64];
    int t = threadIdx.x;
    int lane = t & 63, w = t >> 6;
    int e = 0, base = 0, cnt = n;
    if (EXPERT) { e = blockIdx.y; base = eoff[e]; cnt = eoff[e + 1] - base; }
    int rs = blockIdx.x * 64;
    if (rs >= cnt) return;
    int nrows = min(64, cnt - rs);
    if (t < 64) {
        int j = rs + min(t, nrows - 1);
        rows[t] = EXPERT ? perm[base + j] : j;
    }
    __syncthreads();
    f32x4 acc[4][CT];
#pragma unroll
    for (int rt = 0; rt < 4; ++rt)
#pragma unroll
        for (int ct = 0; ct < CT; ++ct) acc[rt][ct] = (f32x4)(0.f);

    gemm_half<DIN, M0, CT>(A0, B0T + (EXPERT ? (size_t)e * DIN * NCOL : 0), Ah, Bs, rows, acc, t, lane, w);
    gemm_half<DIN, M1, CT>(A1, B1T, Ah, Bs, rows, acc, t, lane, w);

    int q = lane >> 4, m16 = lane & 15;
#pragma unroll
    for (int ct = 0; ct < CT; ++ct) {
        int col = w * CT * 16 + ct * 16 + m16;
        float bv = bias[(EXPERT ? e * NCOL : 0) + col];
#pragma unroll
        for (int rt = 0; rt < 4; ++rt)
#pragma unroll
            for (int i = 0; i < 4; ++i) {
                int rr = rt * 16 + q * 4 + i;
                if (rr < nrows) {
                    int gr = rows[rr];
                    float v = acc[rt][ct][i] + bv;
                    if (RELU) v = fmaxf(v, 0.f);
                    if (OUTMODE == 1) ((unsigned short*)outp)[(size_t)gr * NCOL + col] = f2bf(v);
                    else if (OUTMODE == 0) ((float*)outp)[(size_t)gr * NCOL + col] = v;
                    else {
                        if (col < 128) ((unsigned short*)outp)[(size_t)gr * 128 + col] = f2bf(v);
                        else           ((float*)outp2)[(size_t)gr * 128 + (col - 128)] = v;
                    }
                }
            }
    }
}

__global__ void k_final(const float* __restrict__ gsum, float* __restrict__ outf) {
    if (threadIdx.x == 0 && blockIdx.x == 0) {
        float g = (gsum[0] + gsum[1]) * (0.5f / 50000.0f);
        outf[(size_t)50000 * 128] = g;   // output buffer is fp32
    }
}

extern "C" void kernel_launch(void* const* d_in, const int* in_sizes, int n_in,
                              void* d_out, int out_size, void* d_ws, size_t ws_size,
                              hipStream_t stream) {
    constexpr int N = 50000, E = 800000;
    const float* x   = (const float*)d_in[0];
    const int* ei    = (const int*)d_in[1];
    const float* wg1 = (const float*)d_in[2];
    const float* bg1 = (const float*)d_in[3];
    const float* we1 = (const float*)d_in[4];
    const float* be1 = (const float*)d_in[5];
    const float* wr1 = (const float*)d_in[6];
    const float* wg2 = (const float*)d_in[7];
    const float* bg2 = (const float*)d_in[8];
    const float* we2 = (const float*)d_in[9];
    const float* be2 = (const float*)d_in[10];
    const float* wr2 = (const float*)d_in[11];
    const float* wl3 = (const float*)d_in[12];
    const float* bl3 = (const float*)d_in[13];
    const float* wr3 = (const float*)d_in[14];

    // ---- workspace layout ----
    int* ip = (int*)d_ws;
    int* deg = ip;            ip += N;
    int* cursor = ip;         ip += N;
    int* ecnt = ip;           ip += 16;
    int* ecur = ip;           ip += 16;
    float* gsum = (float*)ip; ip += 2;
    int* flags = ip;          ip += 2;
    float* bias3 = (float*)ip; ip += 256;
    int* row_ptr = ip;        ip += N + 1;
    int* csr = ip;            ip += E;
    int* idxb = ip;           ip += N;
    int* permb = ip;          ip += N;
    int* eoff = ip;           ip += 18;
    int* part = ip;           ip += 256;
    int* src32 = ip;          ip += E;
    int* dst32 = ip;          ip += E;
    size_t off = (size_t)((char*)ip - (char*)d_ws);
    off = (off + 255) & ~(size_t)255;
    float* fp = (float*)((char*)d_ws + off);
    float* G2 = fp; fp += (size_t)N * 8;               // fp32 [N][8] gate-2 pre-logits
    float* agg = fp; fp += (size_t)N * 256;            // fp32 agg (layer 1); bf16 aggb (layer 2); Rf (layer 3)
    float* h1  = fp; fp += (size_t)N * 256;            // bf16 h1b (first half); Pb (second half)
    unsigned short* wp = (unsigned short*)fp;
    unsigned short* h2b  = wp; wp += (size_t)N * 256;  // bf16 h2 (gate-free)
    unsigned short* we2T = wp; wp += 8 * 256 * 256;    // bf16 B^T [n][k]
    unsigned short* wr2T = wp; wp += 256 * 256;
    unsigned short* wl3T = wp; wp += 256 * 128;
    unsigned short* wr3T = wp; wp += 256 * 128;
    unsigned short* aggb = (unsigned short*)agg;       // bf16 [N][256] (aliases agg; layer-2 A)
    unsigned short* h1b  = (unsigned short*)h1;        // bf16 [N][256]
    unsigned short* Pb = (unsigned short*)(h1 + (size_t)N * 128);  // bf16 [N][128], 2nd half of h1 region
    float* Rf = agg;                                   // fp32 [N][128] (aggb dead by layer-3)

    hipMemsetAsync(d_ws, 0, (size_t)(2 * N + 36) * 4, stream);

    k_detect<<<1, 64, 0, stream>>>(ei, flags);
    k_cvt_idx<<<(E + 255) / 256, 256, 0, stream>>>(ei, src32, dst32, deg, E, flags);

    // fused transpose+narrow to bf16 B^T [n][k] (layers 2/3)
    k_transpose_nb<<<dim3(8, 8, 8), 256, 0, stream>>>(we2, we2T, 256, 256);
    k_transpose_nb<<<dim3(8, 8, 1), 256, 0, stream>>>(wr2, wr2T, 256, 256);
    k_transpose_nb<<<dim3(4, 8, 1), 256, 0, stream>>>(wl3, wl3T, 256, 128);
    k_transpose_nb<<<dim3(4, 8, 1), 256, 0, stream>>>(wr3, wr3T, 256, 128);
    k_bias3<<<1, 256, 0, stream>>>(bl3, bias3);

    // CSR (degree fused into k_cvt_idx)
    constexpr int NB = (N + 255) / 256;
    constexpr int WB = (N + 3) / 4;
    k_scan1<<<NB, 256, 0, stream>>>(deg, row_ptr, part, N);
    k_scan2<<<1, 256, 0, stream>>>(part, NB);
    k_scan3<<<NB, 256, 0, stream>>>(row_ptr, part, N, E);
    k_fill<<<(E + 255) / 256, 256, 0, stream>>>(src32, dst32, row_ptr, cursor, csr, E);

    constexpr int GB = (N + 63) / 64;      // 64-row tiles (MFMA layers 2/3)
    constexpr int GB32 = (N + 31) / 32;    // 32-row tiles (VALU layer 1, compact grid)
    // ---- layer 1: 128 -> 256, MoE + root(x), relu — VALU fp32; h1b bf16 + G2 fp32 out ----
    k_aggr<128><<<WB, 256, 0, stream>>>(x, row_ptr, csr, agg, N);
    k_gate<128><<<NB, 256, 0, stream>>>(agg, wg1, bg1, idxb, ecnt, gsum, N);
    k_offsets<<<1, 1, 0, stream>>>(ecnt, eoff);
    k_perm<<<NB, 256, 0, stream>>>(idxb, eoff, ecur, permb, N);
    k_gemm_f32<128, 256, true><<<dim3(GB32), 256, 0, stream>>>(
        agg, x, we1, wr1, be1, wg2, permb, eoff, h1b, G2, N);

    // ---- layer 2: 256 -> 256, MoE + root(h1), relu — gate from G2; bf16 gather; MODE-2 GEMM ----
    k_gate_g<<<NB, 256, 0, stream>>>(G2, row_ptr, csr, bg2, idxb, ecnt + 8, gsum + 1, N);
    k_aggr_h1b<<<WB, 256, 0, stream>>>(h1b, row_ptr, csr, aggb, N);
    k_offsets<<<1, 1, 0, stream>>>(ecnt + 8, eoff + 9);
    k_perm<<<NB, 256, 0, stream>>>(idxb, eoff + 9, ecur + 8, permb, N);
    k_gemm<256, 2, 2, 4, true, true, 1><<<dim3(GB, 8), 256, 0, stream>>>(
        aggb, h1b, we2T, wr2T, be2, permb, eoff + 9, h2b, nullptr, N);

    // ---- layer 3 (linearity swap): [P|R] = h2b @ [wl3|wr3]; out = mean_aggr(P) + R ----
    k_gemm<256, 2, 9, 4, false, false, 2><<<dim3(GB, 1), 256, 0, stream>>>(
        h2b, nullptr, wl3T, nullptr, bias3, nullptr, nullptr, Pb, Rf, N);
    k_aggr_badd<<<WB, 256, 0, stream>>>(Pb, row_ptr, csr, Rf, (float*)d_out, N);

    k_final<<<1, 1, 0, stream>>>(gsum, (float*)d_out);
}

// Round 12
// 612.075 us; speedup vs baseline: 1.0989x; 1.0130x over previous
//
#include <hip/hip_runtime.h>
#include <hip/hip_bf16.h>
#include <stdint.h>

#define DEV static __device__ __forceinline__

typedef __attribute__((ext_vector_type(8))) short short8;   // 8 bf16 (4 VGPRs)
typedef __attribute__((ext_vector_type(4))) float f32x4;    // MFMA accumulator
typedef __attribute__((ext_vector_type(2))) float f32x2;    // v_pk_fma_f32 pair

DEV float bf2f(unsigned short u) { return __uint_as_float(((unsigned)u) << 16); }
DEV float bflo(unsigned u) { return __uint_as_float(u << 16); }
DEV float bfhi(unsigned u) { return __uint_as_float(u & 0xffff0000u); }
DEV unsigned short f2bf(float f) {
    unsigned u = __float_as_uint(f);
    u += 0x7fff + ((u >> 16) & 1);   // RNE
    return (unsigned short)(u >> 16);
}

// ---------------- edge_index width detection (int64 vs int32) ----------------
__global__ void k_detect(const int* __restrict__ ei, int* __restrict__ flags) {
    if (threadIdx.x == 0 && blockIdx.x == 0) {
        int zeros = 0;
        for (int i = 0; i < 128; ++i) if (ei[2 * i + 1] == 0) ++zeros;
        flags[1] = (zeros >= 64) ? 1 : 0;
    }
}

// fused: index narrow + degree count (saves a separate 800k-element pass)
__global__ void k_cvt_idx(const int* __restrict__ ei, int* __restrict__ src32,
                          int* __restrict__ dst32, int* __restrict__ deg,
                          int E, const int* __restrict__ flags) {
    int i = blockIdx.x * 256 + threadIdx.x;
    if (i >= E) return;
    int s, d;
    if (flags[1]) { s = ei[2 * i]; d = ei[2 * E + 2 * i]; }
    else          { s = ei[i];     d = ei[E + i]; }
    src32[i] = s; dst32[i] = d;
    atomicAdd(&deg[d], 1);
}

// ---------------- fused transpose+narrow: fp32 in[r][c] -> bf16 out[c][r] ----------------
__global__ void k_transpose_nb(const float* __restrict__ in, unsigned short* __restrict__ out,
                               int R, int C) {
    __shared__ unsigned short tile[32][33];
    int tx = threadIdx.x & 31, ty = threadIdx.x >> 5;   // 256 threads = 32x8
    size_t mat = (size_t)blockIdx.z * R * C;
    int r0 = blockIdx.y * 32, c0 = blockIdx.x * 32;
#pragma unroll
    for (int j = 0; j < 32; j += 8)
        tile[ty + j][tx] = f2bf(in[mat + (size_t)(r0 + ty + j) * C + c0 + tx]);
    __syncthreads();
#pragma unroll
    for (int j = 0; j < 32; j += 8)
        out[mat + (size_t)(c0 + ty + j) * R + r0 + tx] = tile[tx][ty + j];
}

// bias for the fused layer-3 GEMM: cols 0..127 (P half) get 0, cols 128..255 get bl3
__global__ void k_bias3(const float* __restrict__ bl3, float* __restrict__ bias3) {
    int t = threadIdx.x;
    bias3[t] = (t < 128) ? 0.f : bl3[t - 128];
}

// ---------------- CSR build: degree (fused above) -> 3-phase shfl scan -> fill ----------------
__global__ void k_scan1(const int* __restrict__ deg, int* __restrict__ row_ptr,
                        int* __restrict__ part, int n) {
    __shared__ int wsum[4];
    int t = threadIdx.x, lane = t & 63, wv = t >> 6;
    int i = blockIdx.x * 256 + t;
    int v0 = (i < n) ? deg[i] : 0;
    int v = v0;
#pragma unroll
    for (int d = 1; d < 64; d <<= 1) { int u = __shfl_up(v, d); if (lane >= d) v += u; }
    if (lane == 63) wsum[wv] = v;
    __syncthreads();
    int add = 0;
    for (int w2 = 0; w2 < wv; ++w2) add += wsum[w2];
    v += add;
    if (i < n) row_ptr[i] = v - v0;            // block-local exclusive
    if (t == 255) part[blockIdx.x] = v;        // block total
}

__global__ void k_scan2(int* __restrict__ part, int P) {
    __shared__ int wsum[4];
    int t = threadIdx.x, lane = t & 63, wv = t >> 6;
    int v0 = (t < P) ? part[t] : 0;
    int v = v0;
#pragma unroll
    for (int d = 1; d < 64; d <<= 1) { int u = __shfl_up(v, d); if (lane >= d) v += u; }
    if (lane == 63) wsum[wv] = v;
    __syncthreads();
    int add = 0;
    for (int w2 = 0; w2 < wv; ++w2) add += wsum[w2];
    v += add;
    if (t < P) part[t] = v - v0;               // exclusive over partials
}

__global__ void k_scan3(int* __restrict__ row_ptr, const int* __restrict__ part, int n, int E) {
    int i = blockIdx.x * 256 + threadIdx.x;
    if (i < n) row_ptr[i] += part[blockIdx.x];
    if (i == 0) row_ptr[n] = E;
}

__global__ void k_fill(const int* __restrict__ src, const int* __restrict__ dst,
                       const int* __restrict__ row_ptr, int* __restrict__ cursor,
                       int* __restrict__ csr, int E) {
    int i = blockIdx.x * 256 + threadIdx.x;
    if (i < E) {
        int d = dst[i];
        int p = atomicAdd(&cursor[d], 1);
        csr[row_ptr[d] + p] = src[i];
    }
}
// NOTE (round-16): per-list src sort tried — FETCH unchanged, +94 us. Reverted.
// NOTE (round-17): compact-grid MFMA MoE GEMM tried — +18 us. Reverted.
// NOTE (round-18): 8-row gather unroll: +3% only — bandwidth-proportional.
// NOTE (round-20): fp32 2-phase G2 reduce recovered 29 us. Round-21/22: v_pk_fma_f32
// (packed fp32) in the layer-1 K loop — scalar fp32 issues at 78.6 TF, packed at
// 157 TF; per-output FMA order unchanged -> h1 bit-identical.
// (round-21 bench was an infra failure — this is an unchanged resubmit.)

// ---------------- mean aggregation: one wave/node, fp64 accumulate, 8-row unroll ----------------
template<int D>
__global__ __launch_bounds__(256, 2) void k_aggr(
    const float* __restrict__ xin, const int* __restrict__ row_ptr,
    const int* __restrict__ csr, float* __restrict__ agg, int n) {
    int wid = (blockIdx.x * blockDim.x + threadIdx.x) >> 6;
    int lane = threadIdx.x & 63;
    if (wid >= n) return;
    constexpr int V = D / 64;
    double ac[8][V];
#pragma unroll
    for (int r = 0; r < 8; ++r)
#pragma unroll
        for (int i = 0; i < V; ++i) ac[r][i] = 0.0;
    int s0 = row_ptr[wid], s1 = row_ptr[wid + 1];
    int j = s0;
    for (; j + 8 <= s1; j += 8) {
        const float* p[8];
#pragma unroll
        for (int r = 0; r < 8; ++r) p[r] = xin + (size_t)csr[j + r] * D + lane * V;
        if (V == 2) {
            float2 f[8];
#pragma unroll
            for (int r = 0; r < 8; ++r) f[r] = *(const float2*)p[r];
#pragma unroll
            for (int r = 0; r < 8; ++r) { ac[r][0] += (double)f[r].x; ac[r][1] += (double)f[r].y; }
        } else {
            float4 f[8];
#pragma unroll
            for (int r = 0; r < 8; ++r) f[r] = *(const float4*)p[r];
#pragma unroll
            for (int r = 0; r < 8; ++r) {
                ac[r][0] += (double)f[r].x; ac[r][1] += (double)f[r].y;
                ac[r][2] += (double)f[r].z; ac[r][3] += (double)f[r].w;
            }
        }
    }
    for (; j + 4 <= s1; j += 4) {
        const float* p[4];
#pragma unroll
        for (int r = 0; r < 4; ++r) p[r] = xin + (size_t)csr[j + r] * D + lane * V;
        if (V == 2) {
            float2 f[4];
#pragma unroll
            for (int r = 0; r < 4; ++r) f[r] = *(const float2*)p[r];
#pragma unroll
            for (int r = 0; r < 4; ++r) { ac[r][0] += (double)f[r].x; ac[r][1] += (double)f[r].y; }
        } else {
            float4 f[4];
#pragma unroll
            for (int r = 0; r < 4; ++r) f[r] = *(const float4*)p[r];
#pragma unroll
            for (int r = 0; r < 4; ++r) {
                ac[r][0] += (double)f[r].x; ac[r][1] += (double)f[r].y;
                ac[r][2] += (double)f[r].z; ac[r][3] += (double)f[r].w;
            }
        }
    }
    for (; j < s1; ++j) {
        const float* p = xin + (size_t)csr[j] * D + lane * V;
        if (V == 2) {
            float2 f = *(const float2*)p;
            ac[0][0] += (double)f.x; ac[0][1] += (double)f.y;
        } else {
            float4 f = *(const float4*)p;
            ac[0][0] += (double)f.x; ac[0][1] += (double)f.y;
            ac[0][2] += (double)f.z; ac[0][3] += (double)f.w;
        }
    }
    double inv = 1.0 / (double)max(s1 - s0, 1);
#pragma unroll
    for (int i = 0; i < V; ++i) {
        double s = ((ac[0][i] + ac[1][i]) + (ac[2][i] + ac[3][i]))
                 + ((ac[4][i] + ac[5][i]) + (ac[6][i] + ac[7][i]));
        agg[(size_t)wid * D + lane * V + i] = (float)(s * inv);
    }
}

// Layer-2 gather: reads bf16 h1b (512 B/row, half the fp32 bytes), writes bf16 agg
// for the MODE-2 GEMM stage. Gate-2 no longer depends on this (G2 path).
__global__ __launch_bounds__(256, 2) void k_aggr_h1b(
    const unsigned short* __restrict__ xin, const int* __restrict__ row_ptr,
    const int* __restrict__ csr, unsigned short* __restrict__ aggb, int n) {
    int wid = (blockIdx.x * blockDim.x + threadIdx.x) >> 6;
    int lane = threadIdx.x & 63;
    if (wid >= n) return;
    double ac[8][4];
#pragma unroll
    for (int r = 0; r < 8; ++r)
#pragma unroll
        for (int i = 0; i < 4; ++i) ac[r][i] = 0.0;
    int s0 = row_ptr[wid], s1 = row_ptr[wid + 1];
    int j = s0;
    for (; j + 8 <= s1; j += 8) {
        uint2 u[8];
#pragma unroll
        for (int r = 0; r < 8; ++r) u[r] = *(const uint2*)(xin + (size_t)csr[j + r] * 256 + lane * 4);
#pragma unroll
        for (int r = 0; r < 8; ++r) {
            ac[r][0] += (double)bflo(u[r].x); ac[r][1] += (double)bfhi(u[r].x);
            ac[r][2] += (double)bflo(u[r].y); ac[r][3] += (double)bfhi(u[r].y);
        }
    }
    for (; j + 4 <= s1; j += 4) {
        uint2 u[4];
#pragma unroll
        for (int r = 0; r < 4; ++r) u[r] = *(const uint2*)(xin + (size_t)csr[j + r] * 256 + lane * 4);
#pragma unroll
        for (int r = 0; r < 4; ++r) {
            ac[r][0] += (double)bflo(u[r].x); ac[r][1] += (double)bfhi(u[r].x);
            ac[r][2] += (double)bflo(u[r].y); ac[r][3] += (double)bfhi(u[r].y);
        }
    }
    for (; j < s1; ++j) {
        uint2 u = *(const uint2*)(xin + (size_t)csr[j] * 256 + lane * 4);
        ac[0][0] += (double)bflo(u.x); ac[0][1] += (double)bfhi(u.x);
        ac[0][2] += (double)bflo(u.y); ac[0][3] += (double)bfhi(u.y);
    }
    double inv = 1.0 / (double)max(s1 - s0, 1);
    float m[4];
#pragma unroll
    for (int i = 0; i < 4; ++i) {
        double s = ((ac[0][i] + ac[1][i]) + (ac[2][i] + ac[3][i]))
                 + ((ac[4][i] + ac[5][i]) + (ac[6][i] + ac[7][i]));
        m[i] = (float)(s * inv);
    }
    unsigned b01 = (unsigned)f2bf(m[0]) | ((unsigned)f2bf(m[1]) << 16);
    unsigned b23 = (unsigned)f2bf(m[2]) | ((unsigned)f2bf(m[3]) << 16);
    *(uint2*)(aggb + (size_t)wid * 256 + lane * 4) = make_uint2(b01, b23);
}

// Layer-3 fused gather (8-row unroll): P is bf16 [n][128]; out = mean(P[nbrs]) + R.
__global__ __launch_bounds__(256, 2) void k_aggr_badd(
    const unsigned short* __restrict__ Pb, const int* __restrict__ row_ptr,
    const int* __restrict__ csr, const float* __restrict__ Rf,
    float* __restrict__ outp, int n) {
    int wid = (blockIdx.x * blockDim.x + threadIdx.x) >> 6;
    int lane = threadIdx.x & 63;
    if (wid >= n) return;
    double ac[8][2];
#pragma unroll
    for (int r = 0; r < 8; ++r) { ac[r][0] = 0.0; ac[r][1] = 0.0; }
    int s0 = row_ptr[wid], s1 = row_ptr[wid + 1];
    int j = s0;
    for (; j + 8 <= s1; j += 8) {
        unsigned u[8];
#pragma unroll
        for (int r = 0; r < 8; ++r) u[r] = *(const unsigned*)(Pb + (size_t)csr[j + r] * 128 + lane * 2);
#pragma unroll
        for (int r = 0; r < 8; ++r) { ac[r][0] += (double)bflo(u[r]); ac[r][1] += (double)bfhi(u[r]); }
    }
    for (; j + 4 <= s1; j += 4) {
        unsigned u[4];
#pragma unroll
        for (int r = 0; r < 4; ++r) u[r] = *(const unsigned*)(Pb + (size_t)csr[j + r] * 128 + lane * 2);
#pragma unroll
        for (int r = 0; r < 4; ++r) { ac[r][0] += (double)bflo(u[r]); ac[r][1] += (double)bfhi(u[r]); }
    }
    for (; j < s1; ++j) {
        unsigned u = *(const unsigned*)(Pb + (size_t)csr[j] * 128 + lane * 2);
        ac[0][0] += (double)bflo(u); ac[0][1] += (double)bfhi(u);
    }
    double inv = 1.0 / (double)max(s1 - s0, 1);
    float2 r2 = *(const float2*)(Rf + (size_t)wid * 128 + lane * 2);
    float2 o;
    o.x = (float)((((ac[0][0] + ac[1][0]) + (ac[2][0] + ac[3][0]))
                 + ((ac[4][0] + ac[5][0]) + (ac[6][0] + ac[7][0]))) * inv) + r2.x;
    o.y = (float)((((ac[0][1] + ac[1][1]) + (ac[2][1] + ac[3][1]))
                 + ((ac[4][1] + ac[5][1]) + (ac[6][1] + ac[7][1]))) * inv) + r2.y;
    *(float2*)(outp + (size_t)wid * 128 + lane * 2) = o;
}

// ---------------- gate-1 (round-5 verbatim; fp32 weights read directly) ----------------
template<int D>
__global__ void k_gate(const float* __restrict__ agg, const float* __restrict__ wg,
                       const float* __restrict__ bg, int* __restrict__ idx,
                       int* __restrict__ ecnt, float* __restrict__ gsum, int n) {
    __shared__ float swg[D * 8];
    __shared__ int hcnt[8];
    __shared__ float red[256];
    int t = threadIdx.x;
    if (t < 8) hcnt[t] = 0;
    for (int i = t; i < D * 8; i += 256) swg[i] = wg[i];
    __syncthreads();
    int nid = blockIdx.x * 256 + t;
    float stdv = 0.f;
    if (nid < n) {
        double lg[8];
#pragma unroll
        for (int e = 0; e < 8; ++e) lg[e] = (double)bg[e];
        const float* ap = agg + (size_t)nid * D;
        for (int k = 0; k < D; k += 4) {
            float4 a = *(const float4*)(ap + k);
#pragma unroll
            for (int e = 0; e < 8; ++e) {
                lg[e] += (double)a.x * swg[(k + 0) * 8 + e] + (double)a.y * swg[(k + 1) * 8 + e]
                       + (double)a.z * swg[(k + 2) * 8 + e] + (double)a.w * swg[(k + 3) * 8 + e];
            }
        }
        double m = lg[0];
        int am = 0;
#pragma unroll
        for (int e = 1; e < 8; ++e) if (lg[e] > m) { m = lg[e]; am = e; }
        double s = 0.0, p[8];
#pragma unroll
        for (int e = 0; e < 8; ++e) { p[e] = exp(lg[e] - m); s += p[e]; }
        double invs = 1.0 / s, sq = 0.0;
#pragma unroll
        for (int e = 0; e < 8; ++e) { double q = p[e] * invs; sq += q * q; }
        stdv = (float)sqrt(fmax(sq - 0.125, 0.0) / 7.0);
        idx[nid] = am;
        atomicAdd(&hcnt[am], 1);
    }
    red[t] = stdv;
    __syncthreads();
    for (int off = 128; off > 0; off >>= 1) {
        if (t < off) red[t] += red[t + off];
        __syncthreads();
    }
    if (t == 0) atomicAdd(gsum, red[0]);
    if (t < 8 && hcnt[t] > 0) atomicAdd(&ecnt[t], hcnt[t]);
}

// ---------------- gate-2 from G2 (fp32 [N][8], linearity swap) ----------------
__global__ void k_gate_g(const float* __restrict__ G2, const int* __restrict__ row_ptr,
                         const int* __restrict__ csr, const float* __restrict__ bg,
                         int* __restrict__ idx, int* __restrict__ ecnt,
                         float* __restrict__ gsum, int n) {
    __shared__ int hcnt[8];
    __shared__ float red[256];
    int t = threadIdx.x;
    if (t < 8) hcnt[t] = 0;
    __syncthreads();
    int nid = blockIdx.x * 256 + t;
    float stdv = 0.f;
    if (nid < n) {
        double lg[8];
#pragma unroll
        for (int e = 0; e < 8; ++e) lg[e] = 0.0;
        int s0 = row_ptr[nid], s1 = row_ptr[nid + 1];
        for (int j = s0; j < s1; ++j) {
            const float* g = G2 + (size_t)csr[j] * 8;
            float4 g0 = *(const float4*)g, g1 = *(const float4*)(g + 4);
            lg[0] += (double)g0.x; lg[1] += (double)g0.y; lg[2] += (double)g0.z; lg[3] += (double)g0.w;
            lg[4] += (double)g1.x; lg[5] += (double)g1.y; lg[6] += (double)g1.z; lg[7] += (double)g1.w;
        }
        double inv = 1.0 / (double)max(s1 - s0, 1);
#pragma unroll
        for (int e = 0; e < 8; ++e) lg[e] = lg[e] * inv + (double)bg[e];
        double m = lg[0];
        int am = 0;
#pragma unroll
        for (int e = 1; e < 8; ++e) if (lg[e] > m) { m = lg[e]; am = e; }
        double s = 0.0, p[8];
#pragma unroll
        for (int e = 0; e < 8; ++e) { p[e] = exp(lg[e] - m); s += p[e]; }
        double invs = 1.0 / s, sq = 0.0;
#pragma unroll
        for (int e = 0; e < 8; ++e) { double q = p[e] * invs; sq += q * q; }
        stdv = (float)sqrt(fmax(sq - 0.125, 0.0) / 7.0);
        idx[nid] = am;
        atomicAdd(&hcnt[am], 1);
    }
    red[t] = stdv;
    __syncthreads();
    for (int off = 128; off > 0; off >>= 1) {
        if (t < off) red[t] += red[t + off];
        __syncthreads();
    }
    if (t == 0) atomicAdd(gsum, red[0]);
    if (t < 8 && hcnt[t] > 0) atomicAdd(&ecnt[t], hcnt[t]);
}

__global__ void k_offsets(const int* __restrict__ ecnt, int* __restrict__ eoff) {
    if (threadIdx.x == 0 && blockIdx.x == 0) {
        int s = 0;
        for (int e = 0; e < 8; ++e) { eoff[e] = s; s += ecnt[e]; }
        eoff[8] = s;
    }
}

__global__ void k_perm(const int* __restrict__ idx, const int* __restrict__ eoff,
                       int* __restrict__ ecur, int* __restrict__ perm, int n) {
    __shared__ int lcnt[8], lbase[8];
    int t = threadIdx.x;
    if (t < 8) lcnt[t] = 0;
    __syncthreads();
    int nid = blockIdx.x * 256 + t;
    int e = 0, r = 0;
    bool valid = (nid < n);
    if (valid) { e = idx[nid]; r = atomicAdd(&lcnt[e], 1); }
    __syncthreads();
    if (t < 8) lbase[t] = lcnt[t] ? atomicAdd(&ecur[t], lcnt[t]) : 0;
    __syncthreads();
    if (valid) perm[eoff[e] + lbase[e] + r] = nid;
}

// ---------------- VALU fp32 GEMM, layer 1 (compact grid; h1 bit-identical) ----------
// Round-21/22: inner loop on f32x2 + __builtin_elementwise_fma -> v_pk_fma_f32
// (2 fp32 FMA/instr; scalar fp32 tops at 78.6 TF, packed at 157). Per-output FMA
// k-order unchanged; each pair element is an independent IEEE fp32 fma -> h1
// bit-identical. Epilogue: h1b bf16 store + fp32 G2 2-phase reduce (round-20).
template<int NCOL, bool LOAD>
DEV void g_step(int g, const float* __restrict__ Bp, const float* __restrict__ at,
                float4 (&cur)[4], f32x2 (&acc)[8][2]) {
    f32x2 bx[4][2];
#pragma unroll
    for (int kk = 0; kk < 4; ++kk) {
        bx[kk][0] = f32x2{cur[kk].x, cur[kk].y};
        bx[kk][1] = f32x2{cur[kk].z, cur[kk].w};
    }
#pragma unroll
    for (int r = 0; r < 8; ++r) {
        float4 a = *(const float4*)(at + r * 68 + g * 4);   // uniform addr -> LDS broadcast
        f32x2 a0 = {a.x, a.x}, a1 = {a.y, a.y}, a2 = {a.z, a.z}, a3 = {a.w, a.w};
#pragma unroll
        for (int c = 0; c < 2; ++c) {
            acc[r][c] = __builtin_elementwise_fma(a0, bx[0][c], acc[r][c]);
            acc[r][c] = __builtin_elementwise_fma(a1, bx[1][c], acc[r][c]);
            acc[r][c] = __builtin_elementwise_fma(a2, bx[2][c], acc[r][c]);
            acc[r][c] = __builtin_elementwise_fma(a3, bx[3][c], acc[r][c]);
        }
    }
    if (LOAD) {
#pragma unroll
        for (int kk = 0; kk < 4; ++kk)
            cur[kk] = *(const float4*)(Bp + (size_t)(g * 4 + 8 + kk) * NCOL);
    }
}

template<int NCOL>
DEV void compute_chunk(const float* __restrict__ Bp, const float* __restrict__ at,
                       f32x2 (&acc)[8][2]) {
    float4 bA[4], bB[4];
#pragma unroll
    for (int kk = 0; kk < 4; ++kk) bA[kk] = *(const float4*)(Bp + (size_t)kk * NCOL);
#pragma unroll
    for (int kk = 0; kk < 4; ++kk) bB[kk] = *(const float4*)(Bp + (size_t)(4 + kk) * NCOL);
#pragma unroll 1
    for (int g = 0; g < 14; g += 2) {          // rolled: keep body small for I$
        g_step<NCOL, true>(g, Bp, at, bA, acc);
        g_step<NCOL, true>(g + 1, Bp, at, bB, acc);
    }
    g_step<NCOL, false>(14, Bp, at, bA, acc);
    g_step<NCOL, false>(15, Bp, at, bB, acc);
}

template<int DIN, int NCOL, bool RELU>
__global__ __launch_bounds__(256, 4) void k_gemm_f32(
    const float* __restrict__ agg, const float* __restrict__ a2,
    const float* __restrict__ B1, const float* __restrict__ B2,
    const float* __restrict__ bias, const float* __restrict__ wg2,
    const int* __restrict__ perm, const int* __restrict__ eoff,
    unsigned short* __restrict__ h1b, float* __restrict__ G2, int n) {
    static_assert(DIN == 128 && NCOL == 256, "layer-1 geometry");
    __shared__ float a_tile[2][4 * 8 * 68];
    __shared__ int rows[32];
    int t = threadIdx.x;
    int rs = blockIdx.x * 32;
    if (rs >= n) return;
    int nrows = min(32, n - rs);
    if (t < 32) rows[t] = perm[rs + min(t, nrows - 1)];
    __syncthreads();                            // the only barrier in this kernel

    int e0 = 0, e1 = 0;
    int last = rs + nrows - 1;
#pragma unroll
    for (int e = 1; e < 8; ++e) {
        int v = eoff[e];
        if (v <= rs) e0 = e;
        if (v <= last) e1 = e;
    }
    int ne = e1 - e0 + 1;
    int nchunks = 2 * ne + 2;

    int lane = t & 63, rg = t >> 6;
    int cols = lane * 4;
    int srow = lane >> 3;                       // 0..7 within wave
    int sk = (lane & 7) * 8;                    // 0..56
    int gpos = rs + rg * 8 + srow;              // global perm position of my staged row
    int myrow = rows[rg * 8 + srow];
    float* stc = &a_tile[0][rg * 544 + srow * 68 + sk];
    float* stn = &a_tile[1][rg * 544 + srow * 68 + sk];
    const float* atc = &a_tile[0][rg * 544];
    const float* atn = &a_tile[1][rg * 544];

    f32x2 acc[8][2];
#pragma unroll
    for (int r = 0; r < 8; ++r) { acc[r][0] = (f32x2)(0.f); acc[r][1] = (f32x2)(0.f); }

    auto params = [&](int c, const float*& ap, const float*& Bp, float& m) {
        int half = c & 1;
        if (c < 2 * ne) {
            int e = e0 + (c >> 1);
            ap = agg + (size_t)myrow * DIN + sk + half * 64;
            Bp = B1 + (size_t)e * DIN * NCOL + (size_t)half * 64 * NCOL + cols;
            m = (gpos >= eoff[e] && gpos < eoff[e + 1]) ? 1.f : 0.f;
        } else {
            ap = a2 + (size_t)myrow * DIN + sk + half * 64;
            Bp = B2 + (size_t)half * 64 * NCOL + cols;
            m = 1.f;
        }
    };

    const float* ap; const float* Bp; float m;
    params(0, ap, Bp, m);
    float4 p0 = *(const float4*)ap, p1 = *(const float4*)(ap + 4);
#pragma unroll 1
    for (int c = 0; c < nchunks; ++c) {
        float4 s0 = p0, s1 = p1;
        s0.x *= m; s0.y *= m; s0.z *= m; s0.w *= m;
        s1.x *= m; s1.y *= m; s1.z *= m; s1.w *= m;
        *(float4*)stc = s0; *(float4*)(stc + 4) = s1;
        const float* Bcur = Bp;
        if (c + 1 < nchunks) {                  // prefetch next chunk's A (hidden under compute)
            params(c + 1, ap, Bp, m);
            p0 = *(const float4*)ap; p1 = *(const float4*)(ap + 4);
        }
        compute_chunk<NCOL>(Bcur, atc, acc);
        float* ts = stc; stc = stn; stn = ts;
        const float* ta = atc; atc = atn; atn = ta;
    }

    // epilogue-only wg2 registers (loaded late -> no main-loop VGPR pressure)
    float wreg[4][8];
    {
        const float* wp2 = wg2 + (size_t)cols * 8;
#pragma unroll
        for (int c = 0; c < 4; ++c) {
            float4 wa = *(const float4*)(wp2 + c * 8);
            float4 wb = *(const float4*)(wp2 + c * 8 + 4);
            wreg[c][0] = wa.x; wreg[c][1] = wa.y; wreg[c][2] = wa.z; wreg[c][3] = wa.w;
            wreg[c][4] = wb.x; wreg[c][5] = wb.y; wreg[c][6] = wb.z; wreg[c][7] = wb.w;
        }
    }
    int ksel = lane & 7;

#pragma unroll
    for (int r = 0; r < 8; ++r) {
        int rr = rg * 8 + r;                    // wave-uniform -> shfl-safe guard
        if (rr < nrows) {
            int gp = rs + rr;
            int er = e0;
            for (int e = e0 + 1; e <= e1; ++e) if (eoff[e] <= gp) er = e;
            float4 bb = *(const float4*)(bias + er * NCOL + cols);
            int gr = rows[rr];
            float v0 = acc[r][0].x + bb.x, v1 = acc[r][0].y + bb.y;
            float v2 = acc[r][1].x + bb.z, v3 = acc[r][1].y + bb.w;
            if (RELU) { v0 = fmaxf(v0, 0.f); v1 = fmaxf(v1, 0.f); v2 = fmaxf(v2, 0.f); v3 = fmaxf(v3, 0.f); }
            unsigned b01 = (unsigned)f2bf(v0) | ((unsigned)f2bf(v1) << 16);
            unsigned b23 = (unsigned)f2bf(v2) | ((unsigned)f2bf(v3) << 16);
            *(uint2*)(h1b + (size_t)gr * NCOL + cols) = make_uint2(b01, b23);
            // fp32 gate-2 partials, 2-phase butterfly reduce
            float pf[8];
#pragma unroll
            for (int e = 0; e < 8; ++e)
                pf[e] = v0 * wreg[0][e] + v1 * wreg[1][e] + v2 * wreg[2][e] + v3 * wreg[3][e];
#pragma unroll
            for (int off = 1; off < 8; off <<= 1)
#pragma unroll
                for (int e = 0; e < 8; ++e) pf[e] += __shfl_xor(pf[e], off);
            // select expert (lane&7) — compile-time chain, no scratch
            float v = pf[0];
            if (ksel == 1) v = pf[1];
            if (ksel == 2) v = pf[2];
            if (ksel == 3) v = pf[3];
            if (ksel == 4) v = pf[4];
            if (ksel == 5) v = pf[5];
            if (ksel == 6) v = pf[6];
            if (ksel == 7) v = pf[7];
#pragma unroll
            for (int off = 8; off < 64; off <<= 1) v += __shfl_xor(v, off);
            if (lane < 8) G2[(size_t)gr * 8 + lane] = v;
        }
    }
}

// ---------------- MFMA GEMM (layers 2/3). MODE 0: fp32 A -> f2bf in LDS.
// MODE 2: A already bf16, direct stage. MODE 9: half skipped entirely.
template<int DIN, int MODE, int CT>
DEV void gemm_half(const void* __restrict__ Asrc, const unsigned short* __restrict__ BT,
                   short (*Ah)[40], short (*Bs)[40],
                   const int* rows, f32x4 (&acc)[4][CT], int t, int lane, int w) {
    if (MODE == 9) return;
    int q = lane >> 4, m16 = lane & 15;
    int r = t >> 2, part = t & 3;
    for (int kc = 0; kc < DIN; kc += 32) {
        __syncthreads();
        if (MODE == 2) {
            *(uint4*)&Ah[r][part * 8] =
                *(const uint4*)((const unsigned short*)Asrc + (size_t)rows[r] * DIN + kc + part * 8);
        } else {
            const float* pf = (const float*)Asrc + (size_t)rows[r] * DIN + kc + part * 8;
            float4 p0 = *(const float4*)pf, p1 = *(const float4*)(pf + 4);
            float va[8] = { p0.x, p0.y, p0.z, p0.w, p1.x, p1.y, p1.z, p1.w };
            short8 h;
#pragma unroll
            for (int j = 0; j < 8; ++j) h[j] = (short)f2bf(va[j]);
            *(short8*)&Ah[r][part * 8] = h;
        }
#pragma unroll
        for (int j = 0; j < CT; ++j) {
            int c = t + 256 * j;
            int nn = c >> 2, pp = c & 3;
            *(uint4*)&Bs[nn][pp * 8] = *(const uint4*)(BT + (size_t)nn * DIN + kc + pp * 8);
        }
        __syncthreads();
        short8 af[4], bfr[CT];
#pragma unroll
        for (int rt = 0; rt < 4; ++rt) af[rt] = *(short8*)&Ah[rt * 16 + m16][q * 8];
#pragma unroll
        for (int ct = 0; ct < CT; ++ct) bfr[ct] = *(short8*)&Bs[w * CT * 16 + ct * 16 + m16][q * 8];
#pragma unroll
        for (int rt = 0; rt < 4; ++rt)
#pragma unroll
            for (int ct = 0; ct < CT; ++ct)
                acc[rt][ct] = __builtin_amdgcn_mfma_f32_16x16x32_bf16(af[rt], bfr[ct], acc[rt][ct], 0, 0, 0);
    }
}

// OUTMODE: 0 = fp32 store, 1 = bf16 store, 2 = split (cols<128 -> bf16 outp stride 128,
// cols>=128 -> fp32 outp2 stride 128; bias carries [0|bl3])
template<int DIN, int M0, int M1, int CT, bool EXPERT, bool RELU, int OUTMODE>
__global__ __launch_bounds__(256) void k_gemm(
    const void* __restrict__ A0, const void* __restrict__ A1,
    const unsigned short* __restrict__ B0T, const unsigned short* __restrict__ B1T,
    const float* __restrict__ bias,
    const int* __restrict__ perm, const int* __restrict__ eoff,
    void* __restrict__ outp, void* __restrict__ outp2, int n) {
    constexpr int NCOL = CT * 64;
    __shared__ short Ah[64][40];
    __shared__ short Bs[NCOL][40];
    __shared__ int rows[64];
    int t = threadIdx.x;
    int lane = t & 63, w = t >> 6;
    int e = 0, base = 0, cnt = n;
    if (EXPERT) { e = blockIdx.y; base = eoff[e]; cnt = eoff[e + 1] - base; }
    int rs = blockIdx.x * 64;
    if (rs >= cnt) return;
    int nrows = min(64, cnt - rs);
    if (t < 64) {
        int j = rs + min(t, nrows - 1);
        rows[t] = EXPERT ? perm[base + j] : j;
    }
    __syncthreads();
    f32x4 acc[4][CT];
#pragma unroll
    for (int rt = 0; rt < 4; ++rt)
#pragma unroll
        for (int ct = 0; ct < CT; ++ct) acc[rt][ct] = (f32x4)(0.f);

    gemm_half<DIN, M0, CT>(A0, B0T + (EXPERT ? (size_t)e * DIN * NCOL : 0), Ah, Bs, rows, acc, t, lane, w);
    gemm_half<DIN, M1, CT>(A1, B1T, Ah, Bs, rows, acc, t, lane, w);

    int q = lane >> 4, m16 = lane & 15;
#pragma unroll
    for (int ct = 0; ct < CT; ++ct) {
        int col = w * CT * 16 + ct * 16 + m16;
        float bv = bias[(EXPERT ? e * NCOL : 0) + col];
#pragma unroll
        for (int rt = 0; rt < 4; ++rt)
#pragma unroll
            for (int i = 0; i < 4; ++i) {
                int rr = rt * 16 + q * 4 + i;
                if (rr < nrows) {
                    int gr = rows[rr];
                    float v = acc[rt][ct][i] + bv;
                    if (RELU) v = fmaxf(v, 0.f);
                    if (OUTMODE == 1) ((unsigned short*)outp)[(size_t)gr * NCOL + col] = f2bf(v);
                    else if (OUTMODE == 0) ((float*)outp)[(size_t)gr * NCOL + col] = v;
                    else {
                        if (col < 128) ((unsigned short*)outp)[(size_t)gr * 128 + col] = f2bf(v);
                        else           ((float*)outp2)[(size_t)gr * 128 + (col - 128)] = v;
                    }
                }
            }
    }
}

__global__ void k_final(const float* __restrict__ gsum, float* __restrict__ outf) {
    if (threadIdx.x == 0 && blockIdx.x == 0) {
        float g = (gsum[0] + gsum[1]) * (0.5f / 50000.0f);
        outf[(size_t)50000 * 128] = g;   // output buffer is fp32
    }
}

extern "C" void kernel_launch(void* const* d_in, const int* in_sizes, int n_in,
                              void* d_out, int out_size, void* d_ws, size_t ws_size,
                              hipStream_t stream) {
    constexpr int N = 50000, E = 800000;
    const float* x   = (const float*)d_in[0];
    const int* ei    = (const int*)d_in[1];
    const float* wg1 = (const float*)d_in[2];
    const float* bg1 = (const float*)d_in[3];
    const float* we1 = (const float*)d_in[4];
    const float* be1 = (const float*)d_in[5];
    const float* wr1 = (const float*)d_in[6];
    const float* wg2 = (const float*)d_in[7];
    const float* bg2 = (const float*)d_in[8];
    const float* we2 = (const float*)d_in[9];
    const float* be2 = (const float*)d_in[10];
    const float* wr2 = (const float*)d_in[11];
    const float* wl3 = (const float*)d_in[12];
    const float* bl3 = (const float*)d_in[13];
    const float* wr3 = (const float*)d_in[14];

    // ---- workspace layout ----
    int* ip = (int*)d_ws;
    int* deg = ip;            ip += N;
    int* cursor = ip;         ip += N;
    int* ecnt = ip;           ip += 16;
    int* ecur = ip;           ip += 16;
    float* gsum = (float*)ip; ip += 2;
    int* flags = ip;          ip += 2;
    float* bias3 = (float*)ip; ip += 256;
    int* row_ptr = ip;        ip += N + 1;
    int* csr = ip;            ip += E;
    int* idxb = ip;           ip += N;
    int* permb = ip;          ip += N;
    int* eoff = ip;           ip += 18;
    int* part = ip;           ip += 256;
    int* src32 = ip;          ip += E;
    int* dst32 = ip;          ip += E;
    size_t off = (size_t)((char*)ip - (char*)d_ws);
    off = (off + 255) & ~(size_t)255;
    float* fp = (float*)((char*)d_ws + off);
    float* G2 = fp; fp += (size_t)N * 8;               // fp32 [N][8] gate-2 pre-logits
    float* agg = fp; fp += (size_t)N * 256;            // fp32 agg (layer 1); bf16 aggb (layer 2); Rf (layer 3)
    float* h1  = fp; fp += (size_t)N * 256;            // bf16 h1b (first half); Pb (second half)
    unsigned short* wp = (unsigned short*)fp;
    unsigned short* h2b  = wp; wp += (size_t)N * 256;  // bf16 h2 (gate-free)
    unsigned short* we2T = wp; wp += 8 * 256 * 256;    // bf16 B^T [n][k]
    unsigned short* wr2T = wp; wp += 256 * 256;
    unsigned short* wl3T = wp; wp += 256 * 128;
    unsigned short* wr3T = wp; wp += 256 * 128;
    unsigned short* aggb = (unsigned short*)agg;       // bf16 [N][256] (aliases agg; layer-2 A)
    unsigned short* h1b  = (unsigned short*)h1;        // bf16 [N][256]
    unsigned short* Pb = (unsigned short*)(h1 + (size_t)N * 128);  // bf16 [N][128], 2nd half of h1 region
    float* Rf = agg;                                   // fp32 [N][128] (aggb dead by layer-3)

    hipMemsetAsync(d_ws, 0, (size_t)(2 * N + 36) * 4, stream);

    k_detect<<<1, 64, 0, stream>>>(ei, flags);
    k_cvt_idx<<<(E + 255) / 256, 256, 0, stream>>>(ei, src32, dst32, deg, E, flags);

    // fused transpose+narrow to bf16 B^T [n][k] (layers 2/3)
    k_transpose_nb<<<dim3(8, 8, 8), 256, 0, stream>>>(we2, we2T, 256, 256);
    k_transpose_nb<<<dim3(8, 8, 1), 256, 0, stream>>>(wr2, wr2T, 256, 256);
    k_transpose_nb<<<dim3(4, 8, 1), 256, 0, stream>>>(wl3, wl3T, 256, 128);
    k_transpose_nb<<<dim3(4, 8, 1), 256, 0, stream>>>(wr3, wr3T, 256, 128);
    k_bias3<<<1, 256, 0, stream>>>(bl3, bias3);

    // CSR (degree fused into k_cvt_idx)
    constexpr int NB = (N + 255) / 256;
    constexpr int WB = (N + 3) / 4;
    k_scan1<<<NB, 256, 0, stream>>>(deg, row_ptr, part, N);
    k_scan2<<<1, 256, 0, stream>>>(part, NB);
    k_scan3<<<NB, 256, 0, stream>>>(row_ptr, part, N, E);
    k_fill<<<(E + 255) / 256, 256, 0, stream>>>(src32, dst32, row_ptr, cursor, csr, E);

    constexpr int GB = (N + 63) / 64;      // 64-row tiles (MFMA layers 2/3)
    constexpr int GB32 = (N + 31) / 32;    // 32-row tiles (VALU layer 1, compact grid)
    // ---- layer 1: 128 -> 256, MoE + root(x), relu — packed-fp32 VALU; h1b bf16 + G2 out ----
    k_aggr<128><<<WB, 256, 0, stream>>>(x, row_ptr, csr, agg, N);
    k_gate<128><<<NB, 256, 0, stream>>>(agg, wg1, bg1, idxb, ecnt, gsum, N);
    k_offsets<<<1, 1, 0, stream>>>(ecnt, eoff);
    k_perm<<<NB, 256, 0, stream>>>(idxb, eoff, ecur, permb, N);
    k_gemm_f32<128, 256, true><<<dim3(GB32), 256, 0, stream>>>(
        agg, x, we1, wr1, be1, wg2, permb, eoff, h1b, G2, N);

    // ---- layer 2: 256 -> 256, MoE + root(h1), relu — gate from G2; bf16 gather; MODE-2 GEMM ----
    k_gate_g<<<NB, 256, 0, stream>>>(G2, row_ptr, csr, bg2, idxb, ecnt + 8, gsum + 1, N);
    k_aggr_h1b<<<WB, 256, 0, stream>>>(h1b, row_ptr, csr, aggb, N);
    k_offsets<<<1, 1, 0, stream>>>(ecnt + 8, eoff + 9);
    k_perm<<<NB, 256, 0, stream>>>(idxb, eoff + 9, ecur + 8, permb, N);
    k_gemm<256, 2, 2, 4, true, true, 1><<<dim3(GB, 8), 256, 0, stream>>>(
        aggb, h1b, we2T, wr2T, be2, permb, eoff + 9, h2b, nullptr, N);

    // ---- layer 3 (linearity swap): [P|R] = h2b @ [wl3|wr3]; out = mean_aggr(P) + R ----
    k_gemm<256, 2, 9, 4, false, false, 2><<<dim3(GB, 1), 256, 0, stream>>>(
        h2b, nullptr, wl3T, nullptr, bias3, nullptr, nullptr, Pb, Rf, N);
    k_aggr_badd<<<WB, 256, 0, stream>>>(Pb, row_ptr, csr, Rf, (float*)d_out, N);

    k_final<<<1, 1, 0, stream>>>(gsum, (float*)d_out);
}